// Round 10
// baseline (319.115 us; speedup 1.0000x reference)
//
#include <hip/hip_runtime.h>

#define D_ 1024
#define T_ 2048
#define B_ 2
#define H_ 16
#define MLP_ 4096
#define NTOK (B_*T_)   // 4096
#define QG 256         // global q-rows per batch (T/8)
#define L2E 1.44269504088896340736f

typedef float f32x4 __attribute__((ext_vector_type(4)));
typedef __bf16 bf16x8 __attribute__((ext_vector_type(8)));

__device__ __forceinline__ unsigned short f2bf(float f) {
  unsigned int u = __float_as_uint(f);
  u += 0x7fff + ((u >> 16) & 1);
  return (unsigned short)(u >> 16);
}

__device__ __forceinline__ float wave_sum(float v) {
  for (int o = 32; o > 0; o >>= 1) v += __shfl_down(v, o, 64);
  return v;
}

// async global->LDS, 16B per lane; LDS dest = wave-uniform base + lane*16
__device__ __forceinline__ void gload16(const unsigned short* g, unsigned short* l) {
  __builtin_amdgcn_global_load_lds(
      (const __attribute__((address_space(1))) void*)g,
      (__attribute__((address_space(3))) void*)l, 16, 0, 0);
}

// 32-bit LDS byte offset of a __shared__ pointer
__device__ __forceinline__ unsigned ldsoff(const void* p) {
  return (unsigned)(size_t)(const __attribute__((address_space(3))) void*)p;
}

// OPAQUE asm staging (R8/R9 proven +9%): global_load_lds_dwordx4 with
// M0 = wave-uniform LDS base (HW adds lane*16). Compiler sees no vmem->LDS
// write, so its waitcnt pass inserts no conservative drains between the
// t+2 prefetch into the currently-read buffer and the phase ds_reads.
__device__ __forceinline__ void agload16(const unsigned short* g, unsigned m0v) {
  unsigned su = __builtin_amdgcn_readfirstlane(m0v);
  asm volatile("s_mov_b32 m0, %0\n\t"
               "global_load_lds_dwordx4 %1, off"
               :: "s"(su), "v"(g) : "memory");
}

// -------- fused: all 4 weight casts + LN1 in ONE launch ------------------
#define N4_WIN  786432   // 3*D*D/4
#define N4_WOUT 262144   // D*D/4
#define N4_W1   1048576  // MLP*D/4
#define N4_W2   1048576  // D*MLP/4
#define NCASTB  12288    // (sum of above)/256
__global__ void castln_kernel(const float* __restrict__ w_in,
                              const float* __restrict__ w_out,
                              const float* __restrict__ w1,
                              const float* __restrict__ w2,
                              unsigned short* __restrict__ o_in,
                              unsigned short* __restrict__ o_out,
                              unsigned short* __restrict__ o1,
                              unsigned short* __restrict__ o2,
                              const float* __restrict__ x,
                              const float* __restrict__ g,
                              const float* __restrict__ b,
                              unsigned short* __restrict__ xn) {
  int blk = blockIdx.x;
  int tid = threadIdx.x;
  if (blk < NTOK) {
    int wave = tid >> 6, lane = tid & 63;
    float4 v = ((const float4*)(x + (size_t)blk * D_))[tid];
    float s  = v.x + v.y + v.z + v.w;
    float s2 = v.x*v.x + v.y*v.y + v.z*v.z + v.w*v.w;
    s = wave_sum(s); s2 = wave_sum(s2);
    __shared__ float r1[4], r2[4];
    if (lane == 0) { r1[wave] = s; r2[wave] = s2; }
    __syncthreads();
    float ts  = r1[0] + r1[1] + r1[2] + r1[3];
    float ts2 = r2[0] + r2[1] + r2[2] + r2[3];
    float mean = ts * (1.0f / D_);
    float var  = ts2 * (1.0f / D_) - mean * mean;
    float rs = rsqrtf(var + 1e-5f);
    float4 gv = ((const float4*)g)[tid];
    float4 bv = ((const float4*)b)[tid];
    ushort4 o;
    o.x = f2bf((v.x - mean) * rs * gv.x + bv.x);
    o.y = f2bf((v.y - mean) * rs * gv.y + bv.y);
    o.z = f2bf((v.z - mean) * rs * gv.z + bv.z);
    o.w = f2bf((v.w - mean) * rs * gv.w + bv.w);
    ((ushort4*)(xn + (size_t)blk * D_))[tid] = o;
  } else {
    int i = (blk - NTOK) * 256 + tid;
    const float* src; unsigned short* dst; int j = i;
    if (i < N4_WIN) { src = w_in; dst = o_in; }
    else if ((j -= N4_WIN) < N4_WOUT) { src = w_out; dst = o_out; }
    else if ((j -= N4_WOUT) < N4_W1) { src = w1; dst = o1; }
    else { j -= N4_W1; src = w2; dst = o2; }
    float4 v = ((const float4*)src)[j];
    ushort4 o;
    o.x = f2bf(v.x); o.y = f2bf(v.y); o.z = f2bf(v.z); o.w = f2bf(v.w);
    ((ushort4*)dst)[j] = o;
  }
}

// ---- out-proj reduce (2 slabs) + residual + bias + LayerNorm2 -----------
__global__ void reduce_ln_kernel(const float* __restrict__ part,
                                 const float* __restrict__ x,
                                 const float* __restrict__ bias,
                                 const float* __restrict__ g,
                                 const float* __restrict__ b,
                                 float* __restrict__ x1,
                                 unsigned short* __restrict__ xn2) {
  int row = blockIdx.x;
  int tid = threadIdx.x;
  int wave = tid >> 6, lane = tid & 63;
  size_t base = (size_t)row * (D_ / 4) + tid;
  float4 v = ((const float4*)x)[base];
  float4 bo = ((const float4*)bias)[tid];
  v.x += bo.x; v.y += bo.y; v.z += bo.z; v.w += bo.w;
#pragma unroll
  for (int c = 0; c < 2; ++c) {
    float4 p = ((const float4*)part)[(size_t)c * (NTOK * (D_ / 4)) + base];
    v.x += p.x; v.y += p.y; v.z += p.z; v.w += p.w;
  }
  ((float4*)x1)[base] = v;
  float s  = v.x + v.y + v.z + v.w;
  float s2 = v.x*v.x + v.y*v.y + v.z*v.z + v.w*v.w;
  s = wave_sum(s); s2 = wave_sum(s2);
  __shared__ float r1[4], r2[4];
  if (lane == 0) { r1[wave] = s; r2[wave] = s2; }
  __syncthreads();
  float ts  = r1[0] + r1[1] + r1[2] + r1[3];
  float ts2 = r2[0] + r2[1] + r2[2] + r2[3];
  float mean = ts * (1.0f / D_);
  float var  = ts2 * (1.0f / D_) - mean * mean;
  float rs = rsqrtf(var + 1e-5f);
  float4 gv = ((const float4*)g)[tid];
  float4 bv = ((const float4*)b)[tid];
  ushort4 o;
  o.x = f2bf((v.x - mean) * rs * gv.x + bv.x);
  o.y = f2bf((v.y - mean) * rs * gv.y + bv.y);
  o.z = f2bf((v.z - mean) * rs * gv.z + bv.z);
  o.w = f2bf((v.w - mean) * rs * gv.w + bv.w);
  ((ushort4*)xn2)[base] = o;
}

// ---- final reduce: out = x1 + b2 + sum_{c<2} part[c]  (f32, x4) ---------
__global__ void reduce_out_kernel(const float* __restrict__ part,
                                  const float* __restrict__ x1,
                                  const float* __restrict__ bias,
                                  float* __restrict__ out) {
  int i = blockIdx.x * 256 + threadIdx.x;
  float4 v = ((const float4*)x1)[i];
  float4 bo = ((const float4*)bias)[i & (D_ / 4 - 1)];
  v.x += bo.x; v.y += bo.y; v.z += bo.z; v.w += bo.w;
#pragma unroll
  for (int c = 0; c < 2; ++c) {
    float4 p = ((const float4*)part)[(size_t)c * (NTOK * (D_ / 4)) + i];
    v.x += p.x; v.y += p.y; v.z += p.z; v.w += p.w;
  }
  ((float4*)out)[i] = v;
}

// ====== 128x128 dbuf pipelined bf16 GEMM, OPAQUE staging (2 blk/CU) ======
// (R9-verified; QKV / out-proj / MLP2.)
template<int EPI>
__global__ __launch_bounds__(256)
void gemm128p_kernel(const unsigned short* __restrict__ A, int LDA,
                     const unsigned short* __restrict__ Bm, int LDB,
                     void* __restrict__ Cv, size_t sC, int LDC,
                     const float* __restrict__ bias,
                     unsigned short* __restrict__ aux1,
                     unsigned short* __restrict__ aux2,
                     int K, int nx, int ny) {
  __shared__ __align__(16) unsigned short As[2 * 8192];
  __shared__ __align__(16) unsigned short Bs[2 * 8192];
  const int flat = blockIdx.x;
  const int sxc = nx >> 1;
  const int nSuper = sxc * (ny >> 2);
  int s = flat % nSuper, pos = flat / nSuper;
  int sx = s % sxc, sy = s / sxc;
  const int bx = sx * 2 + (pos & 1);
  const int by = sy * 4 + (pos >> 1);
  const int m0 = by * 128, n0 = bx * 128;
  const int kOff = blockIdx.z * K;
  const int tid = threadIdx.x;
  const int lane = tid & 63, wave = tid >> 6;
  const int wm = (wave >> 1) * 64, wn = (wave & 1) * 64;
  const int fr = lane & 15, q = lane >> 4;
  const int f0 = ((q)     ^ (fr & 7)) << 3;
  const int f1 = ((4 + q) ^ (fr & 7)) << 3;

  const unsigned short* aS[4];
  const unsigned short* bS[4];
#pragma unroll
  for (int p = 0; p < 4; ++p) {
    int l = p * 256 + tid;
    int r = l >> 3;
    int cg = (l & 7) ^ (r & 7);
    aS[p] = A  + (size_t)(m0 + r) * LDA + kOff + cg * 8;
    bS[p] = Bm + (size_t)(n0 + r) * LDB + kOff + cg * 8;
  }
  const int NT = K >> 6;

  const unsigned aW = ldsoff(As) + wave * 1024;
  const unsigned bW = ldsoff(Bs) + wave * 1024;

#pragma unroll
  for (int p = 0; p < 4; ++p) {
    agload16(aS[p], aW + p * 4096);
    agload16(bS[p], bW + p * 4096);
  }
#pragma unroll
  for (int p = 0; p < 4; ++p) {
    agload16(aS[p] + 64, aW + 16384 + p * 4096);
    agload16(bS[p] + 64, bW + 16384 + p * 4096);
  }
  asm volatile("s_waitcnt vmcnt(8)");
  __builtin_amdgcn_sched_barrier(0);
  __builtin_amdgcn_s_barrier();

  f32x4 acc[4][4] = {};
  for (int t = 0; t < NT; ++t) {
    const int cb = (t & 1) << 13;
    const unsigned cbB = (t & 1) << 14;
    const unsigned short* Ab = As + cb;
    const unsigned short* Bb = Bs + cb;
    const int ko2 = (t + 2) << 6;
    {
      bf16x8 af[4], bfr[4];
#pragma unroll
      for (int i = 0; i < 4; ++i) af[i]  = *(const bf16x8*)&Ab[(wm + i * 16 + fr) * 64 + f0];
#pragma unroll
      for (int j = 0; j < 4; ++j) bfr[j] = *(const bf16x8*)&Bb[(wn + j * 16 + fr) * 64 + f0];
#pragma unroll
      for (int i = 0; i < 4; ++i)
#pragma unroll
        for (int j = 0; j < 4; ++j)
          acc[i][j] = __builtin_amdgcn_mfma_f32_16x16x32_bf16(af[i], bfr[j], acc[i][j], 0, 0, 0);
    }
    {
      bf16x8 af[4], bfr[4];
#pragma unroll
      for (int i = 0; i < 4; ++i) af[i]  = *(const bf16x8*)&Ab[(wm + i * 16 + fr) * 64 + f1];
#pragma unroll
      for (int j = 0; j < 4; ++j) bfr[j] = *(const bf16x8*)&Bb[(wn + j * 16 + fr) * 64 + f1];
#pragma unroll
      for (int i = 0; i < 4; ++i)
#pragma unroll
        for (int j = 0; j < 4; ++j)
          acc[i][j] = __builtin_amdgcn_mfma_f32_16x16x32_bf16(af[i], bfr[j], acc[i][j], 0, 0, 0);
    }
    __builtin_amdgcn_s_barrier();
    if (t + 2 < NT) {
#pragma unroll
      for (int p = 0; p < 4; ++p) {
        agload16(aS[p] + ko2, aW + cbB + p * 4096);
        agload16(bS[p] + ko2, bW + cbB + p * 4096);
      }
    }
    if (t + 1 < NT) {
      if (t + 2 < NT) asm volatile("s_waitcnt vmcnt(8)");
      else            asm volatile("s_waitcnt vmcnt(0)");
      __builtin_amdgcn_sched_barrier(0);
    }
    __builtin_amdgcn_s_barrier();
  }

  const int col = lane & 15, rbase = (lane >> 4) * 4;
#pragma unroll
  for (int i = 0; i < 4; ++i) {
#pragma unroll
    for (int j = 0; j < 4; ++j) {
      int gn = n0 + wn + j * 16 + col;
      int gmb = m0 + wm + i * 16 + rbase;
      float bv = (EPI == 2 || EPI == 8) ? bias[gn] : 0.0f;
#pragma unroll
      for (int r = 0; r < 4; ++r) {
        int gm = gmb + r;
        float v = acc[i][j][r] + bv;
        if (EPI == 2) {
          float u = v * (1.5957691216f + 0.0713548162f * v * v);
          float gl = v / (1.0f + exp2f(-L2E * u));
          ((unsigned short*)Cv)[(size_t)gm * LDC + gn] = f2bf(gl);
        } else if (EPI == 7) {
          ((float*)Cv)[(size_t)blockIdx.z * sC + (size_t)gm * LDC + gn] = v;
        } else {
          int sec = gn >> 10;
          int hh = (gn >> 6) & (H_ - 1);
          int dd = gn & 63;
          int t = gm & (T_ - 1);
          int b = gm >> 11;
          unsigned short bf = f2bf(v);
          if (sec == 0) {
            if (!(t & 7))
              aux1[(((size_t)(b * H_ + hh)) * QG + (t >> 3)) * 64 + dd] = bf;
          } else if (sec == 1) {
            aux2[(((size_t)(b * H_ + hh)) * T_ + t) * 64 + dd] = bf;
          } else {
            ((unsigned short*)Cv)[(size_t)gm * D_ + (gn - 2 * D_)] = bf;
          }
        }
      }
    }
  }
}

// ====== 128x256 tile, BK=32, dbuf pipelined, 2-3 blocks/CU (MLP1) ========
// Combines the session's two A/B-proven levers: opaque-staged t+2 pipeline
// (R8: +9%) AND cross-block co-residency (R5/R6: 1/CU=80us vs 2/CU=60us).
// LDS 48KB (A 2x8KB + B 2x16KB) -> 3 blocks/CU capacity; MLP1 grid
// 32x16=512 blocks -> 2 resident/CU. 8 waves (2M x 4N), wave tile 64x64,
// 16 MFMA + 8 ds_read_b128 per K-tile(32) per wave (same ratio as 128p).
// Bank swizzle: rows are 64B (4 chunks); slot = chunk ^ ((row>>1)&3)
// spreads each 8-row bank-class over 4 slots -> 2-way alias (free, m136).
// EPI 2 only: bf16 gelu(acc+bias) store.
__global__ __launch_bounds__(512)
void gemm256b_kernel(const unsigned short* __restrict__ A, int LDA,
                     const unsigned short* __restrict__ Bm, int LDB,
                     unsigned short* __restrict__ Cv, int LDC,
                     const float* __restrict__ bias,
                     int K, int nx) {
  __shared__ __align__(16) unsigned short As[2 * 4096];   // [buf][128][32]
  __shared__ __align__(16) unsigned short Bs[2 * 8192];   // [buf][256][32]
  const int tid = threadIdx.x;
  const int lane = tid & 63, wv = tid >> 6;
  const int wm = (wv >> 2) * 64, wn = (wv & 3) * 64;
  const int fr = lane & 15, q = lane >> 4;

  // XCD-aware swizzle (512 = 8*64, bijective)
  const int nwg = gridDim.x;
  const int bid = blockIdx.x;
  const int l = (bid & 7) * (nwg >> 3) + (bid >> 3);
  const int bx = l % nx, by = l / nx;
  const int m0 = by * 128, n0 = bx * 256;

  // staging sources: thread tid owns A slot tid, B slots tid and 512+tid.
  // slot s of row r holds global chunk (s ^ ((r>>1)&3))  [bank swizzle]
  const int rA = tid >> 2, sA = tid & 3;
  const int cA = sA ^ ((rA >> 1) & 3);
  const unsigned short* aSrc = A  + (size_t)(m0 + rA) * LDA + cA * 8;
  const unsigned short* bSrc0 = Bm + (size_t)(n0 + rA) * LDB + cA * 8;
  const unsigned short* bSrc1 = Bm + (size_t)(n0 + 128 + rA) * LDB + cA * 8;
  const int NT = K >> 5;

  // wave-uniform LDS staging bases; lane*16 added by HW
  const unsigned aWb = ldsoff(As) + wv * 1024;
  const unsigned bWb = ldsoff(Bs) + wv * 1024;

  // prologue: tile0 -> buf0, tile1 -> buf1 (3 loads each)
  agload16(aSrc, aWb);
  agload16(bSrc0, bWb);
  agload16(bSrc1, bWb + 8192);
  agload16(aSrc + 32, aWb + 8192);
  agload16(bSrc0 + 32, bWb + 16384);
  agload16(bSrc1 + 32, bWb + 24576);
  asm volatile("s_waitcnt vmcnt(3)");   // tile0 landed; tile1 in flight
  __builtin_amdgcn_sched_barrier(0);
  __builtin_amdgcn_s_barrier();

  f32x4 acc[4][4] = {};
  for (int t = 0; t < NT; ++t) {
    const unsigned cbA = (t & 1) ? 8192u : 0u;     // bytes
    const unsigned cbB = (t & 1) ? 16384u : 0u;
    const char* Ab = (const char*)As + cbA;
    const char* Bb = (const char*)Bs + cbB;
    const int ko2 = (t + 2) << 5;
    bf16x8 af[4], bfr[4];
#pragma unroll
    for (int i = 0; i < 4; ++i) {
      int ra = wm + i * 16 + fr;
      af[i] = *(const bf16x8*)(Ab + ra * 64 + ((q ^ ((ra >> 1) & 3)) << 4));
    }
#pragma unroll
    for (int j = 0; j < 4; ++j) {
      int rb = wn + j * 16 + fr;
      bfr[j] = *(const bf16x8*)(Bb + rb * 64 + ((q ^ ((rb >> 1) & 3)) << 4));
    }
#pragma unroll
    for (int i = 0; i < 4; ++i)
#pragma unroll
      for (int j = 0; j < 4; ++j)
        acc[i][j] = __builtin_amdgcn_mfma_f32_16x16x32_bf16(af[i], bfr[j], acc[i][j], 0, 0, 0);
    // frag reads of cur buf consumed by MFMAs above
    __builtin_amdgcn_s_barrier();
    if (t + 2 < NT) {
      agload16(aSrc + ko2, aWb + cbA);
      agload16(bSrc0 + ko2, bWb + cbB);
      agload16(bSrc1 + ko2, bWb + cbB + 8192);
    }
    if (t + 1 < NT) {
      if (t + 2 < NT) asm volatile("s_waitcnt vmcnt(3)");   // t+1 landed
      else            asm volatile("s_waitcnt vmcnt(0)");   // tail drain
      __builtin_amdgcn_sched_barrier(0);
    }
    __builtin_amdgcn_s_barrier();
  }

  // epilogue: gelu(acc + bias) -> bf16
  const int col = lane & 15, rbase = (lane >> 4) * 4;
#pragma unroll
  for (int i = 0; i < 4; ++i) {
#pragma unroll
    for (int j = 0; j < 4; ++j) {
      int gn = n0 + wn + j * 16 + col;
      int gmb = m0 + wm + i * 16 + rbase;
      float bv = bias[gn];
#pragma unroll
      for (int r = 0; r < 4; ++r) {
        int gm = gmb + r;
        float v = acc[i][j][r] + bv;
        float u = v * (1.5957691216f + 0.0713548162f * v * v);
        float gl = v / (1.0f + exp2f(-L2E * u));
        Cv[(size_t)gm * LDC + gn] = f2bf(gl);
      }
    }
  }
}

// ---------------- V transpose: v[tok, D] bf16 -> Vt[bh][d][t] bf16 -------
__global__ void vtrans_kernel(const unsigned short* __restrict__ vcomp,
                              unsigned short* __restrict__ Vt) {
  int blk = blockIdx.x;          // B*H*(T/64) = 1024
  int tchunk = blk & 31;
  int bh = blk >> 5;
  int h = bh & (H_ - 1), b = bh >> 4;
  int t0 = tchunk * 64;
  __shared__ unsigned short ls[64][66];
  int tid = threadIdx.x;
#pragma unroll
  for (int it = 0; it < 16; ++it) {
    int linear = it * 256 + tid;
    int d = linear & 63, tl = linear >> 6;
    ls[d][tl] = vcomp[((size_t)(b * T_ + t0 + tl)) * D_ + h * 64 + d];
  }
  __syncthreads();
#pragma unroll
  for (int it = 0; it < 16; ++it) {
    int linear = it * 256 + tid;
    int tl = linear & 63, d = linear >> 6;
    Vt[((size_t)(bh * 64 + d)) * T_ + t0 + tl] = ls[d][tl];
  }
}

// ---------------- Flash attention for global q-rows ----------------------
__global__ __launch_bounds__(256)
void flash_kernel(const unsigned short* __restrict__ Qg,   // [bh][256][64]
                  const unsigned short* __restrict__ Kh,   // [bh][2048][64]
                  const unsigned short* __restrict__ Vt,   // [bh][64][2048]
                  float* __restrict__ Opart,               // [bh][4][256][64]
                  float* __restrict__ ml) {                // [bh][4][256][2]
  const int kc = blockIdx.x, qt = blockIdx.y, bh = blockIdx.z;
  const int tid = threadIdx.x;
  const int lane = tid & 63, w = tid >> 6;
  const int fr = lane & 15, quad = lane >> 4;

  __shared__ __align__(16) unsigned short Qs[64 * 64];     // 8 KB
  __shared__ __align__(16) unsigned short Ks[128 * 64];    // 16 KB
  __shared__ __align__(16) unsigned short Vs[64 * 128];    // 16 KB
  __shared__ __align__(16) unsigned short Ps[4 * 16 * 128];// 16 KB

  const unsigned short* Qbase = Qg + ((size_t)bh * 256 + qt * 64) * 64;
#pragma unroll
  for (int p = 0; p < 2; ++p) {
    int linear = p * 256 + tid;
    int r = linear >> 3, c = linear & 7;
    gload16(Qbase + r * 64 + (c ^ (r & 7)) * 8, &Qs[linear * 8]);
  }

  float m_run[4], l_run[4];
  f32x4 O[4] = {};
#pragma unroll
  for (int r = 0; r < 4; ++r) { m_run[r] = -3.0e38f; l_run[r] = 0.f; }

  const unsigned short* Kc = Kh + ((size_t)bh * T_ + kc * 512) * 64;
  const unsigned short* Vc = Vt + (size_t)bh * 64 * T_ + kc * 512;
  unsigned short* Pw = &Ps[w * 2048];
  const int arow = w * 16 + fr;

  for (int kt = 0; kt < 4; ++kt) {
    __syncthreads();
#pragma unroll
    for (int p = 0; p < 4; ++p) {
      int linear = p * 256 + tid;
      int r = linear >> 3, c = linear & 7;
      gload16(Kc + (size_t)(kt * 128 + r) * 64 + (c ^ (r & 7)) * 8, &Ks[linear * 8]);
    }
#pragma unroll
    for (int p = 0; p < 4; ++p) {
      int linear = p * 256 + tid;
      int r = linear >> 4, c = linear & 15;
      gload16(Vc + (size_t)r * T_ + kt * 128 + (c ^ (r & 7)) * 8, &Vs[linear * 8]);
    }
    __syncthreads();

    f32x4 s[8] = {};
    bf16x8 aq[2];
#pragma unroll
    for (int ks = 0; ks < 2; ++ks)
      aq[ks] = *(const bf16x8*)&Qs[arow * 64 + ((ks * 4 + quad) ^ (fr & 7)) * 8];
#pragma unroll
    for (int nf = 0; nf < 8; ++nf) {
      int krow = nf * 16 + fr;
#pragma unroll
      for (int ks = 0; ks < 2; ++ks) {
        bf16x8 bk = *(const bf16x8*)&Ks[krow * 64 + ((ks * 4 + quad) ^ (fr & 7)) * 8];
        s[nf] = __builtin_amdgcn_mfma_f32_16x16x32_bf16(aq[ks], bk, s[nf], 0, 0, 0);
      }
    }
    float alpha[4], rowsum[4];
#pragma unroll
    for (int r = 0; r < 4; ++r) {
      float mt = -3.0e38f;
#pragma unroll
      for (int nf = 0; nf < 8; ++nf) { s[nf][r] *= 0.125f; mt = fmaxf(mt, s[nf][r]); }
#pragma unroll
      for (int x = 1; x < 16; x <<= 1) mt = fmaxf(mt, __shfl_xor(mt, x, 64));
      float mn = fmaxf(m_run[r], mt);
      alpha[r] = exp2f((m_run[r] - mn) * L2E);
      m_run[r] = mn;
      rowsum[r] = 0.f;
    }
#pragma unroll
    for (int nf = 0; nf < 8; ++nf)
#pragma unroll
      for (int r = 0; r < 4; ++r) {
        float p = exp2f((s[nf][r] - m_run[r]) * L2E);
        s[nf][r] = p; rowsum[r] += p;
      }
#pragma unroll
    for (int r = 0; r < 4; ++r) {
#pragma unroll
      for (int x = 1; x < 16; x <<= 1) rowsum[r] += __shfl_xor(rowsum[r], x, 64);
      l_run[r] = l_run[r] * alpha[r] + rowsum[r];
    }
#pragma unroll
    for (int nf = 0; nf < 8; ++nf)
#pragma unroll
      for (int r = 0; r < 4; ++r) {
        int m = quad * 4 + r;
        int c = nf * 2 + (fr >> 3);
        Pw[m * 128 + ((c ^ (m & 7)) * 8) + (fr & 7)] = f2bf(s[nf][r]);
      }
#pragma unroll
    for (int nf2 = 0; nf2 < 4; ++nf2)
#pragma unroll
      for (int r = 0; r < 4; ++r) O[nf2][r] *= alpha[r];
#pragma unroll
    for (int ks2 = 0; ks2 < 4; ++ks2) {
      bf16x8 ap = *(const bf16x8*)&Pw[fr * 128 + (((ks2 * 4 + quad) ^ (fr & 7)) * 8)];
#pragma unroll
      for (int nf2 = 0; nf2 < 4; ++nf2) {
        int vrow = nf2 * 16 + fr;
        bf16x8 bv = *(const bf16x8*)&Vs[vrow * 128 + (((ks2 * 4 + quad) ^ (fr & 7)) * 8)];
        O[nf2] = __builtin_amdgcn_mfma_f32_16x16x32_bf16(ap, bv, O[nf2], 0, 0, 0);
      }
    }
  }

  int qbase = qt * 64 + w * 16;
  float* Ob = Opart + (((size_t)bh * 4 + kc) * 256 + qbase) * 64;
#pragma unroll
  for (int nf2 = 0; nf2 < 4; ++nf2)
#pragma unroll
    for (int r = 0; r < 4; ++r)
      Ob[(size_t)(quad * 4 + r) * 64 + nf2 * 16 + fr] = O[nf2][r];
  if (fr == 0) {
#pragma unroll
    for (int r = 0; r < 4; ++r) {
      size_t mi = ((((size_t)bh * 4 + kc) * 256) + qbase + quad * 4 + r) * 2;
      ml[mi] = m_run[r]; ml[mi + 1] = l_run[r];
    }
  }
}

// ---- combine 4 k-chunk flash partials, scatter into v buffer ------------
__global__ void combine_kernel(const float* __restrict__ Opart,
                               const float* __restrict__ ml,
                               unsigned short* __restrict__ vcomp) {
  int idx = blockIdx.x * 256 + threadIdx.x;  // B*QG*D = 2^19
  int c = idx & (D_ - 1);
  int qi = (idx >> 10) & (QG - 1);
  int b = idx >> 18;
  int h = c >> 6, d = c & 63;
  int bh = b * H_ + h;
  float m[4], l[4];
  float M = -3.0e38f;
#pragma unroll
  for (int ch = 0; ch < 4; ++ch) {
    size_t r = ((size_t)bh * 4 + ch) * 256 + qi;
    m[ch] = ml[r * 2]; l[ch] = ml[r * 2 + 1];
    M = fmaxf(M, m[ch]);
  }
  float osum = 0.f, lsum = 0.f;
#pragma unroll
  for (int ch = 0; ch < 4; ++ch) {
    size_t r = ((size_t)bh * 4 + ch) * 256 + qi;
    float wgt = exp2f((m[ch] - M) * L2E);
    osum += wgt * Opart[r * 64 + d];
    lsum += wgt * l[ch];
  }
  vcomp[((size_t)(b * T_ + qi * 8)) * D_ + c] = f2bf(osum / lsum);
}

extern "C" void kernel_launch(void* const* d_in, const int* in_sizes, int n_in,
                              void* d_out, int out_size, void* d_ws, size_t ws_size,
                              hipStream_t stream) {
  const float* x     = (const float*)d_in[0];
  const float* w_in  = (const float*)d_in[1];
  const float* b_in  = (const float*)d_in[2];
  const float* w_out = (const float*)d_in[3];
  const float* b_out = (const float*)d_in[4];
  const float* w1    = (const float*)d_in[5];
  const float* b1    = (const float*)d_in[6];
  const float* w2    = (const float*)d_in[7];
  const float* b2    = (const float*)d_in[8];
  const float* ln1_g = (const float*)d_in[9];
  const float* ln1_b = (const float*)d_in[10];
  const float* ln2_g = (const float*)d_in[11];
  const float* ln2_b = (const float*)d_in[12];
  float* out = (float*)d_out;

  char* ws = (char*)d_ws;
  size_t off = 0;
  auto alloc = [&](size_t bytes) -> void* {
    void* p = ws + off;
    off += (bytes + 255) & ~(size_t)255;
    return p;
  };
  // persistent-region buffers
  unsigned short* w_inb = (unsigned short*)alloc((size_t)3 * D_ * D_ * 2);
  unsigned short* w_outb= (unsigned short*)alloc((size_t)D_ * D_ * 2);
  unsigned short* w1b   = (unsigned short*)alloc((size_t)MLP_ * D_ * 2);
  unsigned short* w2b   = (unsigned short*)alloc((size_t)D_ * MLP_ * 2);
  unsigned short* vcomp = (unsigned short*)alloc((size_t)NTOK * D_ * 2);  // v, then o
  float*          x1    = (float*)         alloc((size_t)NTOK * D_ * 4);
  unsigned short* xn2   = (unsigned short*)alloc((size_t)NTOK * D_ * 2);
  unsigned short* h     = (unsigned short*)alloc((size_t)NTOK * MLP_ * 2);
  // union region: P2 (2 f32 slabs, 32MB) aliases the attention buffers
  char* U = (char*)alloc((size_t)40 * 1024 * 1024);
  float*          P2    = (float*)U;                                  // 32 MB
  unsigned short* xn    = (unsigned short*)U;                         // 8.0 MB
  unsigned short* Qg    = (unsigned short*)(U + 8388608);             // 4.0 MB
  unsigned short* Kh    = (unsigned short*)(U + 12582912);            // 8.0 MB
  unsigned short* Vt    = (unsigned short*)(U + 20971520);            // 8.0 MB
  float*          Opart = (float*)         (U + 29360128);            // 8.0 MB
  float*          mlbuf = (float*)         (U + 37748736);            // 0.25MB

  // 1. fused weight casts + LN1 (single launch)
  castln_kernel<<<NTOK + NCASTB, 256, 0, stream>>>(
      w_in, w_out, w1, w2, w_inb, w_outb, w1b, w2b, x, ln1_g, ln1_b, xn);

  // 2. QKV = xn @ w_in^T + b_in; routes q->Qg, k->Kh, v->vcomp
  gemm128p_kernel<8><<<dim3(24 * 32, 1, 1), 256, 0, stream>>>(
      xn, D_, w_inb, D_, vcomp, 0, 3 * D_, b_in, Qg, Kh, 1024, 24, 32);

  // 3. V transpose for PV B-operand
  vtrans_kernel<<<1024, 256, 0, stream>>>(vcomp, Vt);

  // 4. flash attention over global q-rows (k-split x4 -> 512 blocks)
  flash_kernel<<<dim3(4, 4, 32), 256, 0, stream>>>(Qg, Kh, Vt, Opart, mlbuf);

  // 5. combine k-chunks, scatter into v buffer (o = v elsewhere)
  combine_kernel<<<2048, 256, 0, stream>>>(Opart, mlbuf, vcomp);

  // 6. P2[c] = o @ w_out^T (split-K x2 -> 512 blocks = 2/CU, NT=8)
  gemm128p_kernel<7><<<dim3(8 * 32, 1, 2), 256, 0, stream>>>(
      vcomp, D_, w_outb, D_, P2, (size_t)NTOK * D_, D_, nullptr, nullptr, nullptr,
      512, 8, 32);

  // 7. x1 = x + b_out + sum_{c<2}(P2); xn2 = LN2(x1)
  reduce_ln_kernel<<<NTOK, 256, 0, stream>>>(P2, x, b_out, ln2_g, ln2_b, x1, xn2);

  // 8. h = gelu(xn2 @ w1^T + b1)  (128x256 BK=32 pipelined, 512 blk = 2/CU)
  gemm256b_kernel<<<dim3(512, 1, 1), 512, 0, stream>>>(
      xn2, D_, w1b, D_, h, MLP_, b1, 1024, 16);

  // 9. P2[c] = h @ w2^T (split-K x2, gemm128p-opaque, NT=32)
  gemm128p_kernel<7><<<dim3(8 * 32, 1, 2), 256, 0, stream>>>(
      h, MLP_, w2b, MLP_, P2, (size_t)NTOK * D_, D_, nullptr, nullptr, nullptr,
      2048, 8, 32);

  // 10. out = x1 + b2 + sum_{c<2}(P2)
  reduce_out_kernel<<<4096, 256, 0, stream>>>(P2, x1, b2, out);
}

// Round 11
// 314.233 us; speedup vs baseline: 1.0155x; 1.0155x over previous
//
#include <hip/hip_runtime.h>

#define D_ 1024
#define T_ 2048
#define B_ 2
#define H_ 16
#define MLP_ 4096
#define NTOK (B_*T_)   // 4096
#define QG 256         // global q-rows per batch (T/8)
#define L2E 1.44269504088896340736f

typedef float f32x4 __attribute__((ext_vector_type(4)));
typedef __bf16 bf16x8 __attribute__((ext_vector_type(8)));

__device__ __forceinline__ unsigned short f2bf(float f) {
  unsigned int u = __float_as_uint(f);
  u += 0x7fff + ((u >> 16) & 1);
  return (unsigned short)(u >> 16);
}

__device__ __forceinline__ float wave_sum(float v) {
  for (int o = 32; o > 0; o >>= 1) v += __shfl_down(v, o, 64);
  return v;
}

// async global->LDS, 16B per lane; LDS dest = wave-uniform base + lane*16
__device__ __forceinline__ void gload16(const unsigned short* g, unsigned short* l) {
  __builtin_amdgcn_global_load_lds(
      (const __attribute__((address_space(1))) void*)g,
      (__attribute__((address_space(3))) void*)l, 16, 0, 0);
}

// 32-bit LDS byte offset of a __shared__ pointer
__device__ __forceinline__ unsigned ldsoff(const void* p) {
  return (unsigned)(size_t)(const __attribute__((address_space(3))) void*)p;
}

// OPAQUE asm staging (R8/R9 proven +9%): global_load_lds_dwordx4 with
// M0 = wave-uniform LDS base (HW adds lane*16). Compiler sees no vmem->LDS
// write, so its waitcnt pass inserts no conservative drains between the
// t+2 prefetch into the currently-read buffer and the phase ds_reads.
__device__ __forceinline__ void agload16(const unsigned short* g, unsigned m0v) {
  unsigned su = __builtin_amdgcn_readfirstlane(m0v);
  asm volatile("s_mov_b32 m0, %0\n\t"
               "global_load_lds_dwordx4 %1, off"
               :: "s"(su), "v"(g) : "memory");
}

// -------- fused: all 4 weight casts + LN1 in ONE launch ------------------
#define N4_WIN  786432   // 3*D*D/4
#define N4_WOUT 262144   // D*D/4
#define N4_W1   1048576  // MLP*D/4
#define N4_W2   1048576  // D*MLP/4
#define NCASTB  12288    // (sum of above)/256
__global__ void castln_kernel(const float* __restrict__ w_in,
                              const float* __restrict__ w_out,
                              const float* __restrict__ w1,
                              const float* __restrict__ w2,
                              unsigned short* __restrict__ o_in,
                              unsigned short* __restrict__ o_out,
                              unsigned short* __restrict__ o1,
                              unsigned short* __restrict__ o2,
                              const float* __restrict__ x,
                              const float* __restrict__ g,
                              const float* __restrict__ b,
                              unsigned short* __restrict__ xn) {
  int blk = blockIdx.x;
  int tid = threadIdx.x;
  if (blk < NTOK) {
    int wave = tid >> 6, lane = tid & 63;
    float4 v = ((const float4*)(x + (size_t)blk * D_))[tid];
    float s  = v.x + v.y + v.z + v.w;
    float s2 = v.x*v.x + v.y*v.y + v.z*v.z + v.w*v.w;
    s = wave_sum(s); s2 = wave_sum(s2);
    __shared__ float r1[4], r2[4];
    if (lane == 0) { r1[wave] = s; r2[wave] = s2; }
    __syncthreads();
    float ts  = r1[0] + r1[1] + r1[2] + r1[3];
    float ts2 = r2[0] + r2[1] + r2[2] + r2[3];
    float mean = ts * (1.0f / D_);
    float var  = ts2 * (1.0f / D_) - mean * mean;
    float rs = rsqrtf(var + 1e-5f);
    float4 gv = ((const float4*)g)[tid];
    float4 bv = ((const float4*)b)[tid];
    ushort4 o;
    o.x = f2bf((v.x - mean) * rs * gv.x + bv.x);
    o.y = f2bf((v.y - mean) * rs * gv.y + bv.y);
    o.z = f2bf((v.z - mean) * rs * gv.z + bv.z);
    o.w = f2bf((v.w - mean) * rs * gv.w + bv.w);
    ((ushort4*)(xn + (size_t)blk * D_))[tid] = o;
  } else {
    int i = (blk - NTOK) * 256 + tid;
    const float* src; unsigned short* dst; int j = i;
    if (i < N4_WIN) { src = w_in; dst = o_in; }
    else if ((j -= N4_WIN) < N4_WOUT) { src = w_out; dst = o_out; }
    else if ((j -= N4_WOUT) < N4_W1) { src = w1; dst = o1; }
    else { j -= N4_W1; src = w2; dst = o2; }
    float4 v = ((const float4*)src)[j];
    ushort4 o;
    o.x = f2bf(v.x); o.y = f2bf(v.y); o.z = f2bf(v.z); o.w = f2bf(v.w);
    ((ushort4*)dst)[j] = o;
  }
}

// ---- out-proj reduce (2 slabs) + residual + bias + LayerNorm2 -----------
__global__ void reduce_ln_kernel(const float* __restrict__ part,
                                 const float* __restrict__ x,
                                 const float* __restrict__ bias,
                                 const float* __restrict__ g,
                                 const float* __restrict__ b,
                                 float* __restrict__ x1,
                                 unsigned short* __restrict__ xn2) {
  int row = blockIdx.x;
  int tid = threadIdx.x;
  int wave = tid >> 6, lane = tid & 63;
  size_t base = (size_t)row * (D_ / 4) + tid;
  float4 v = ((const float4*)x)[base];
  float4 bo = ((const float4*)bias)[tid];
  v.x += bo.x; v.y += bo.y; v.z += bo.z; v.w += bo.w;
#pragma unroll
  for (int c = 0; c < 2; ++c) {
    float4 p = ((const float4*)part)[(size_t)c * (NTOK * (D_ / 4)) + base];
    v.x += p.x; v.y += p.y; v.z += p.z; v.w += p.w;
  }
  ((float4*)x1)[base] = v;
  float s  = v.x + v.y + v.z + v.w;
  float s2 = v.x*v.x + v.y*v.y + v.z*v.z + v.w*v.w;
  s = wave_sum(s); s2 = wave_sum(s2);
  __shared__ float r1[4], r2[4];
  if (lane == 0) { r1[wave] = s; r2[wave] = s2; }
  __syncthreads();
  float ts  = r1[0] + r1[1] + r1[2] + r1[3];
  float ts2 = r2[0] + r2[1] + r2[2] + r2[3];
  float mean = ts * (1.0f / D_);
  float var  = ts2 * (1.0f / D_) - mean * mean;
  float rs = rsqrtf(var + 1e-5f);
  float4 gv = ((const float4*)g)[tid];
  float4 bv = ((const float4*)b)[tid];
  ushort4 o;
  o.x = f2bf((v.x - mean) * rs * gv.x + bv.x);
  o.y = f2bf((v.y - mean) * rs * gv.y + bv.y);
  o.z = f2bf((v.z - mean) * rs * gv.z + bv.z);
  o.w = f2bf((v.w - mean) * rs * gv.w + bv.w);
  ((ushort4*)xn2)[base] = o;
}

// ---- final reduce: out = x1 + b2 + sum_{c<2} part[c]  (f32, x4) ---------
__global__ void reduce_out_kernel(const float* __restrict__ part,
                                  const float* __restrict__ x1,
                                  const float* __restrict__ bias,
                                  float* __restrict__ out) {
  int i = blockIdx.x * 256 + threadIdx.x;
  float4 v = ((const float4*)x1)[i];
  float4 bo = ((const float4*)bias)[i & (D_ / 4 - 1)];
  v.x += bo.x; v.y += bo.y; v.z += bo.z; v.w += bo.w;
#pragma unroll
  for (int c = 0; c < 2; ++c) {
    float4 p = ((const float4*)part)[(size_t)c * (NTOK * (D_ / 4)) + i];
    v.x += p.x; v.y += p.y; v.z += p.z; v.w += p.w;
  }
  ((float4*)out)[i] = v;
}

// ====== 128x128 dbuf pipelined bf16 GEMM, OPAQUE staging (2 blk/CU) ======
// (R9-verified; out-proj / MLP2 split-K.)
template<int EPI>
__global__ __launch_bounds__(256)
void gemm128p_kernel(const unsigned short* __restrict__ A, int LDA,
                     const unsigned short* __restrict__ Bm, int LDB,
                     void* __restrict__ Cv, size_t sC, int LDC,
                     const float* __restrict__ bias,
                     int K, int nx, int ny) {
  __shared__ __align__(16) unsigned short As[2 * 8192];
  __shared__ __align__(16) unsigned short Bs[2 * 8192];
  const int flat = blockIdx.x;
  const int sxc = nx >> 1;
  const int nSuper = sxc * (ny >> 2);
  int s = flat % nSuper, pos = flat / nSuper;
  int sx = s % sxc, sy = s / sxc;
  const int bx = sx * 2 + (pos & 1);
  const int by = sy * 4 + (pos >> 1);
  const int m0 = by * 128, n0 = bx * 128;
  const int kOff = blockIdx.z * K;
  const int tid = threadIdx.x;
  const int lane = tid & 63, wave = tid >> 6;
  const int wm = (wave >> 1) * 64, wn = (wave & 1) * 64;
  const int fr = lane & 15, q = lane >> 4;
  const int f0 = ((q)     ^ (fr & 7)) << 3;
  const int f1 = ((4 + q) ^ (fr & 7)) << 3;

  const unsigned short* aS[4];
  const unsigned short* bS[4];
#pragma unroll
  for (int p = 0; p < 4; ++p) {
    int l = p * 256 + tid;
    int r = l >> 3;
    int cg = (l & 7) ^ (r & 7);
    aS[p] = A  + (size_t)(m0 + r) * LDA + kOff + cg * 8;
    bS[p] = Bm + (size_t)(n0 + r) * LDB + kOff + cg * 8;
  }
  const int NT = K >> 6;

  const unsigned aW = ldsoff(As) + wave * 1024;
  const unsigned bW = ldsoff(Bs) + wave * 1024;

#pragma unroll
  for (int p = 0; p < 4; ++p) {
    agload16(aS[p], aW + p * 4096);
    agload16(bS[p], bW + p * 4096);
  }
#pragma unroll
  for (int p = 0; p < 4; ++p) {
    agload16(aS[p] + 64, aW + 16384 + p * 4096);
    agload16(bS[p] + 64, bW + 16384 + p * 4096);
  }
  asm volatile("s_waitcnt vmcnt(8)");
  __builtin_amdgcn_sched_barrier(0);
  __builtin_amdgcn_s_barrier();

  f32x4 acc[4][4] = {};
  for (int t = 0; t < NT; ++t) {
    const int cb = (t & 1) << 13;
    const unsigned cbB = (t & 1) << 14;
    const unsigned short* Ab = As + cb;
    const unsigned short* Bb = Bs + cb;
    const int ko2 = (t + 2) << 6;
    {
      bf16x8 af[4], bfr[4];
#pragma unroll
      for (int i = 0; i < 4; ++i) af[i]  = *(const bf16x8*)&Ab[(wm + i * 16 + fr) * 64 + f0];
#pragma unroll
      for (int j = 0; j < 4; ++j) bfr[j] = *(const bf16x8*)&Bb[(wn + j * 16 + fr) * 64 + f0];
#pragma unroll
      for (int i = 0; i < 4; ++i)
#pragma unroll
        for (int j = 0; j < 4; ++j)
          acc[i][j] = __builtin_amdgcn_mfma_f32_16x16x32_bf16(af[i], bfr[j], acc[i][j], 0, 0, 0);
    }
    {
      bf16x8 af[4], bfr[4];
#pragma unroll
      for (int i = 0; i < 4; ++i) af[i]  = *(const bf16x8*)&Ab[(wm + i * 16 + fr) * 64 + f1];
#pragma unroll
      for (int j = 0; j < 4; ++j) bfr[j] = *(const bf16x8*)&Bb[(wn + j * 16 + fr) * 64 + f1];
#pragma unroll
      for (int i = 0; i < 4; ++i)
#pragma unroll
        for (int j = 0; j < 4; ++j)
          acc[i][j] = __builtin_amdgcn_mfma_f32_16x16x32_bf16(af[i], bfr[j], acc[i][j], 0, 0, 0);
    }
    __builtin_amdgcn_s_barrier();
    if (t + 2 < NT) {
#pragma unroll
      for (int p = 0; p < 4; ++p) {
        agload16(aS[p] + ko2, aW + cbB + p * 4096);
        agload16(bS[p] + ko2, bW + cbB + p * 4096);
      }
    }
    if (t + 1 < NT) {
      if (t + 2 < NT) asm volatile("s_waitcnt vmcnt(8)");
      else            asm volatile("s_waitcnt vmcnt(0)");
      __builtin_amdgcn_sched_barrier(0);
    }
    __builtin_amdgcn_s_barrier();
  }

  const int col = lane & 15, rbase = (lane >> 4) * 4;
#pragma unroll
  for (int i = 0; i < 4; ++i) {
#pragma unroll
    for (int j = 0; j < 4; ++j) {
      int gn = n0 + wn + j * 16 + col;
      int gmb = m0 + wm + i * 16 + rbase;
      float bv = (EPI == 2) ? bias[gn] : 0.0f;
#pragma unroll
      for (int r = 0; r < 4; ++r) {
        int gm = gmb + r;
        float v = acc[i][j][r] + bv;
        if (EPI == 2) {
          float u = v * (1.5957691216f + 0.0713548162f * v * v);
          float gl = v / (1.0f + exp2f(-L2E * u));
          ((unsigned short*)Cv)[(size_t)gm * LDC + gn] = f2bf(gl);
        } else {
          ((float*)Cv)[(size_t)blockIdx.z * sC + (size_t)gm * LDC + gn] = v;
        }
      }
    }
  }
}

// ========== 256x256 pipelined GEMM, OPAQUE asm staging (MLP1) ============
// (R8/R9-verified: 47.8us on MLP1; 4 phases/K-tile, t+2 prefetch, counted
// vmcnt(8)/tile, setprio around MFMA, opaque agload16 staging.)
template<int EPI>
__global__ __launch_bounds__(512)
void gemm256a_kernel(const unsigned short* __restrict__ A, int LDA,
                     const unsigned short* __restrict__ Bm, int LDB,
                     void* __restrict__ Cv, size_t sC, int LDC,
                     const float* __restrict__ bias,
                     int K, int nx) {
  __shared__ __align__(16) unsigned short As[2 * 16384];
  __shared__ __align__(16) unsigned short Bs[2 * 16384];
  const int tid = threadIdx.x;
  const int lane = tid & 63, w = tid >> 6;
  const int wm = w >> 2, wn = w & 3;
  const int fr = lane & 15, q = lane >> 4, xr = fr & 7;

  const int nwg = gridDim.x;
  const int bid = blockIdx.x;
  const int l = (bid & 7) * (nwg >> 3) + (bid >> 3);
  const int bx = l % nx, by = l / nx;
  const int m0 = by * 256, n0 = bx * 256;
  const int kOff = blockIdx.z * K;

  const unsigned short* aS[4];
  const unsigned short* bS[4];
#pragma unroll
  for (int s = 0; s < 4; ++s) {
    int ls = s * 512 + tid;
    int r = ls >> 3;
    int cg = (ls & 7) ^ (r & 7);
    aS[s] = A  + (size_t)(m0 + r) * LDA + kOff + cg * 8;
    bS[s] = Bm + (size_t)(n0 + r) * LDB + kOff + cg * 8;
  }
  const int NT = K >> 6;

  const unsigned asb = ldsoff(As), bsb = ldsoff(Bs);
  const unsigned aW = asb + w * 1024, bW = bsb + w * 1024;

#pragma unroll
  for (int s = 0; s < 4; ++s) {
    agload16(aS[s], aW + s * 8192);
    agload16(bS[s], bW + s * 8192);
  }
#pragma unroll
  for (int s = 0; s < 4; ++s) {
    agload16(aS[s] + 64, aW + 32768 + s * 8192);
    agload16(bS[s] + 64, bW + 32768 + s * 8192);
  }
  asm volatile("s_waitcnt vmcnt(8)");
  __builtin_amdgcn_sched_barrier(0);
  __builtin_amdgcn_s_barrier();

  const int aOff = ((wm * 128 + fr) << 7) + ((q ^ xr) << 4);
  const int bOff = ((wn * 64 + fr) << 7) + ((q ^ xr) << 4);

  f32x4 acc[8][4] = {};

  for (int t = 0; t < NT; ++t) {
    const int cb = (t & 1) << 15;
    const char* Ab = (const char*)As + cb;
    const char* Bb = (const char*)Bs + cb;
    const unsigned aWc = aW + cb, bWc = bW + cb;
    const int ko2 = (t + 2) << 6;
    bf16x8 af[2][4], bfr[2][4];

#pragma unroll
    for (int i = 0; i < 4; ++i) {
      af[0][i] = *(const bf16x8*)(Ab + aOff + i * 2048);
      af[1][i] = *(const bf16x8*)(Ab + (aOff ^ 64) + i * 2048);
    }
#pragma unroll
    for (int j = 0; j < 2; ++j) {
      bfr[0][j] = *(const bf16x8*)(Bb + bOff + j * 2048);
      bfr[1][j] = *(const bf16x8*)(Bb + (bOff ^ 64) + j * 2048);
    }
    __builtin_amdgcn_s_barrier();
    __builtin_amdgcn_s_setprio(1);
#pragma unroll
    for (int i = 0; i < 4; ++i)
#pragma unroll
      for (int j = 0; j < 2; ++j) {
        acc[i][j] = __builtin_amdgcn_mfma_f32_16x16x32_bf16(af[0][i], bfr[0][j], acc[i][j], 0, 0, 0);
        acc[i][j] = __builtin_amdgcn_mfma_f32_16x16x32_bf16(af[1][i], bfr[1][j], acc[i][j], 0, 0, 0);
      }
    __builtin_amdgcn_s_setprio(0);
    __builtin_amdgcn_s_barrier();

#pragma unroll
    for (int j = 2; j < 4; ++j) {
      bfr[0][j] = *(const bf16x8*)(Bb + bOff + j * 2048);
      bfr[1][j] = *(const bf16x8*)(Bb + (bOff ^ 64) + j * 2048);
    }
    if (t + 2 < NT) {
      agload16(aS[0] + ko2, aWc);
      agload16(aS[2] + ko2, aWc + 16384);
    }
    __builtin_amdgcn_s_barrier();
    __builtin_amdgcn_s_setprio(1);
#pragma unroll
    for (int i = 0; i < 4; ++i)
#pragma unroll
      for (int j = 0; j < 2; ++j) {
        acc[i][2 + j] = __builtin_amdgcn_mfma_f32_16x16x32_bf16(af[0][i], bfr[0][2 + j], acc[i][2 + j], 0, 0, 0);
        acc[i][2 + j] = __builtin_amdgcn_mfma_f32_16x16x32_bf16(af[1][i], bfr[1][2 + j], acc[i][2 + j], 0, 0, 0);
      }
    __builtin_amdgcn_s_setprio(0);
    __builtin_amdgcn_s_barrier();

#pragma unroll
    for (int i = 0; i < 4; ++i) {
      af[0][i] = *(const bf16x8*)(Ab + (aOff + 8192) + i * 2048);
      af[1][i] = *(const bf16x8*)(Ab + ((aOff + 8192) ^ 64) + i * 2048);
    }
    if (t + 2 < NT) {
      agload16(bS[0] + ko2, bWc);
      agload16(bS[1] + ko2, bWc + 8192);
      agload16(bS[2] + ko2, bWc + 16384);
      agload16(bS[3] + ko2, bWc + 24576);
    }
    __builtin_amdgcn_s_barrier();
    __builtin_amdgcn_s_setprio(1);
#pragma unroll
    for (int i = 0; i < 4; ++i)
#pragma unroll
      for (int j = 0; j < 2; ++j) {
        acc[4 + i][j] = __builtin_amdgcn_mfma_f32_16x16x32_bf16(af[0][i], bfr[0][j], acc[4 + i][j], 0, 0, 0);
        acc[4 + i][j] = __builtin_amdgcn_mfma_f32_16x16x32_bf16(af[1][i], bfr[1][j], acc[4 + i][j], 0, 0, 0);
      }
    __builtin_amdgcn_s_setprio(0);
    __builtin_amdgcn_s_barrier();

    if (t + 2 < NT) {
      agload16(aS[1] + ko2, aWc + 8192);
      agload16(aS[3] + ko2, aWc + 24576);
    }
    if (t + 1 < NT) {
      if (t + 2 < NT) asm volatile("s_waitcnt vmcnt(8)");
      else            asm volatile("s_waitcnt vmcnt(0)");
      __builtin_amdgcn_sched_barrier(0);
    }
    __builtin_amdgcn_s_barrier();
    __builtin_amdgcn_s_setprio(1);
#pragma unroll
    for (int i = 0; i < 4; ++i)
#pragma unroll
      for (int j = 0; j < 2; ++j) {
        acc[4 + i][2 + j] = __builtin_amdgcn_mfma_f32_16x16x32_bf16(af[0][i], bfr[0][2 + j], acc[4 + i][2 + j], 0, 0, 0);
        acc[4 + i][2 + j] = __builtin_amdgcn_mfma_f32_16x16x32_bf16(af[1][i], bfr[1][2 + j], acc[4 + i][2 + j], 0, 0, 0);
      }
    __builtin_amdgcn_s_setprio(0);
    __builtin_amdgcn_s_barrier();
  }

  const int col = lane & 15, rbase = (lane >> 4) * 4;
  const int gm0 = m0 + wm * 128 + rbase;
  const int gn0 = n0 + wn * 64 + col;
#pragma unroll
  for (int mi = 0; mi < 8; ++mi) {
#pragma unroll
    for (int j = 0; j < 4; ++j) {
      int gn = gn0 + j * 16;
      float bv = (EPI == 2) ? bias[gn] : 0.0f;
#pragma unroll
      for (int r = 0; r < 4; ++r) {
        int gm = gm0 + mi * 16 + r;
        float v = acc[mi][j][r] + bv;
        if (EPI == 2) {
          float u = v * (1.5957691216f + 0.0713548162f * v * v);
          float gl = v / (1.0f + exp2f(-L2E * u));
          ((unsigned short*)Cv)[(size_t)gm * LDC + gn] = f2bf(gl);
        } else {
          ((float*)Cv)[(size_t)blockIdx.z * sC + (size_t)gm * LDC + gn] = v;
        }
      }
    }
  }
}

// ====== 128x256 tile, BK=32, dbuf pipelined (QKV) ========================
// R10-verified structure (passed correctness). 48KB LDS -> 3 blocks/CU
// capacity. QKV grid 32x12 = 384 blocks -> ALL co-resident in one round
// (vs 768@128^2 = 1.5 rounds with a half-empty tail). 8 waves (2M x 4N),
// wave tile 64x64, opaque-staged t+2 pipeline, counted vmcnt(3)/K-tile.
// Bank swizzle: slot = chunk ^ ((row>>1)&3) -> 2-way alias (free, m136).
// EPI 2: bf16 gelu(acc+bias); EPI 8: QKV routing (verbatim gemm128p EPI8;
// 256-wide N-tile never straddles q/k/v: 1024 % 256 == 0).
template<int EPI>
__global__ __launch_bounds__(512)
void gemm256b_kernel(const unsigned short* __restrict__ A, int LDA,
                     const unsigned short* __restrict__ Bm, int LDB,
                     unsigned short* __restrict__ Cv, int LDC,
                     const float* __restrict__ bias,
                     unsigned short* __restrict__ aux1,
                     unsigned short* __restrict__ aux2,
                     int K, int nx) {
  __shared__ __align__(16) unsigned short As[2 * 4096];   // [buf][128][32]
  __shared__ __align__(16) unsigned short Bs[2 * 8192];   // [buf][256][32]
  const int tid = threadIdx.x;
  const int lane = tid & 63, wv = tid >> 6;
  const int wm = (wv >> 2) * 64, wn = (wv & 3) * 64;
  const int fr = lane & 15, q = lane >> 4;

  // XCD-aware swizzle (grid multiple of 8 -> bijective)
  const int nwg = gridDim.x;
  const int bid = blockIdx.x;
  const int l = (bid & 7) * (nwg >> 3) + (bid >> 3);
  const int bx = l % nx, by = l / nx;
  const int m0 = by * 128, n0 = bx * 256;

  // staging: thread tid owns A slot tid, B slots tid and 512+tid.
  // slot s of row r holds global chunk (s ^ ((r>>1)&3))  [bank swizzle]
  const int rA = tid >> 2, sA = tid & 3;
  const int cA = sA ^ ((rA >> 1) & 3);
  const unsigned short* aSrc = A  + (size_t)(m0 + rA) * LDA + cA * 8;
  const unsigned short* bSrc0 = Bm + (size_t)(n0 + rA) * LDB + cA * 8;
  const unsigned short* bSrc1 = Bm + (size_t)(n0 + 128 + rA) * LDB + cA * 8;
  const int NT = K >> 5;

  const unsigned aWb = ldsoff(As) + wv * 1024;
  const unsigned bWb = ldsoff(Bs) + wv * 1024;

  // prologue: tile0 -> buf0, tile1 -> buf1 (3 loads each)
  agload16(aSrc, aWb);
  agload16(bSrc0, bWb);
  agload16(bSrc1, bWb + 8192);
  agload16(aSrc + 32, aWb + 8192);
  agload16(bSrc0 + 32, bWb + 16384);
  agload16(bSrc1 + 32, bWb + 24576);
  asm volatile("s_waitcnt vmcnt(3)");
  __builtin_amdgcn_sched_barrier(0);
  __builtin_amdgcn_s_barrier();

  f32x4 acc[4][4] = {};
  for (int t = 0; t < NT; ++t) {
    const unsigned cbA = (t & 1) ? 8192u : 0u;     // bytes
    const unsigned cbB = (t & 1) ? 16384u : 0u;
    const char* Ab = (const char*)As + cbA;
    const char* Bb = (const char*)Bs + cbB;
    const int ko2 = (t + 2) << 5;
    bf16x8 af[4], bfr[4];
#pragma unroll
    for (int i = 0; i < 4; ++i) {
      int ra = wm + i * 16 + fr;
      af[i] = *(const bf16x8*)(Ab + ra * 64 + ((q ^ ((ra >> 1) & 3)) << 4));
    }
#pragma unroll
    for (int j = 0; j < 4; ++j) {
      int rb = wn + j * 16 + fr;
      bfr[j] = *(const bf16x8*)(Bb + rb * 64 + ((q ^ ((rb >> 1) & 3)) << 4));
    }
#pragma unroll
    for (int i = 0; i < 4; ++i)
#pragma unroll
      for (int j = 0; j < 4; ++j)
        acc[i][j] = __builtin_amdgcn_mfma_f32_16x16x32_bf16(af[i], bfr[j], acc[i][j], 0, 0, 0);
    __builtin_amdgcn_s_barrier();
    if (t + 2 < NT) {
      agload16(aSrc + ko2, aWb + cbA);
      agload16(bSrc0 + ko2, bWb + cbB);
      agload16(bSrc1 + ko2, bWb + cbB + 8192);
    }
    if (t + 1 < NT) {
      if (t + 2 < NT) asm volatile("s_waitcnt vmcnt(3)");
      else            asm volatile("s_waitcnt vmcnt(0)");
      __builtin_amdgcn_sched_barrier(0);
    }
    __builtin_amdgcn_s_barrier();
  }

  const int col = lane & 15, rbase = (lane >> 4) * 4;
#pragma unroll
  for (int i = 0; i < 4; ++i) {
#pragma unroll
    for (int j = 0; j < 4; ++j) {
      int gn = n0 + wn + j * 16 + col;
      int gmb = m0 + wm + i * 16 + rbase;
      float bv = bias[gn];
#pragma unroll
      for (int r = 0; r < 4; ++r) {
        int gm = gmb + r;
        float v = acc[i][j][r] + bv;
        if (EPI == 2) {
          float u = v * (1.5957691216f + 0.0713548162f * v * v);
          float gl = v / (1.0f + exp2f(-L2E * u));
          Cv[(size_t)gm * LDC + gn] = f2bf(gl);
        } else {
          int sec = gn >> 10;          // 0=q 1=k 2=v (uniform per block)
          int hh = (gn >> 6) & (H_ - 1);
          int dd = gn & 63;
          int t = gm & (T_ - 1);
          int b = gm >> 11;
          unsigned short bf = f2bf(v);
          if (sec == 0) {
            if (!(t & 7))
              aux1[(((size_t)(b * H_ + hh)) * QG + (t >> 3)) * 64 + dd] = bf;
          } else if (sec == 1) {
            aux2[(((size_t)(b * H_ + hh)) * T_ + t) * 64 + dd] = bf;
          } else {
            Cv[(size_t)gm * D_ + (gn - 2 * D_)] = bf;
          }
        }
      }
    }
  }
}

// ---------------- V transpose: v[tok, D] bf16 -> Vt[bh][d][t] bf16 -------
__global__ void vtrans_kernel(const unsigned short* __restrict__ vcomp,
                              unsigned short* __restrict__ Vt) {
  int blk = blockIdx.x;          // B*H*(T/64) = 1024
  int tchunk = blk & 31;
  int bh = blk >> 5;
  int h = bh & (H_ - 1), b = bh >> 4;
  int t0 = tchunk * 64;
  __shared__ unsigned short ls[64][66];
  int tid = threadIdx.x;
#pragma unroll
  for (int it = 0; it < 16; ++it) {
    int linear = it * 256 + tid;
    int d = linear & 63, tl = linear >> 6;
    ls[d][tl] = vcomp[((size_t)(b * T_ + t0 + tl)) * D_ + h * 64 + d];
  }
  __syncthreads();
#pragma unroll
  for (int it = 0; it < 16; ++it) {
    int linear = it * 256 + tid;
    int tl = linear & 63, d = linear >> 6;
    Vt[((size_t)(bh * 64 + d)) * T_ + t0 + tl] = ls[d][tl];
  }
}

// ---------------- Flash attention for global q-rows ----------------------
__global__ __launch_bounds__(256)
void flash_kernel(const unsigned short* __restrict__ Qg,   // [bh][256][64]
                  const unsigned short* __restrict__ Kh,   // [bh][2048][64]
                  const unsigned short* __restrict__ Vt,   // [bh][64][2048]
                  float* __restrict__ Opart,               // [bh][4][256][64]
                  float* __restrict__ ml) {                // [bh][4][256][2]
  const int kc = blockIdx.x, qt = blockIdx.y, bh = blockIdx.z;
  const int tid = threadIdx.x;
  const int lane = tid & 63, w = tid >> 6;
  const int fr = lane & 15, quad = lane >> 4;

  __shared__ __align__(16) unsigned short Qs[64 * 64];     // 8 KB
  __shared__ __align__(16) unsigned short Ks[128 * 64];    // 16 KB
  __shared__ __align__(16) unsigned short Vs[64 * 128];    // 16 KB
  __shared__ __align__(16) unsigned short Ps[4 * 16 * 128];// 16 KB

  const unsigned short* Qbase = Qg + ((size_t)bh * 256 + qt * 64) * 64;
#pragma unroll
  for (int p = 0; p < 2; ++p) {
    int linear = p * 256 + tid;
    int r = linear >> 3, c = linear & 7;
    gload16(Qbase + r * 64 + (c ^ (r & 7)) * 8, &Qs[linear * 8]);
  }

  float m_run[4], l_run[4];
  f32x4 O[4] = {};
#pragma unroll
  for (int r = 0; r < 4; ++r) { m_run[r] = -3.0e38f; l_run[r] = 0.f; }

  const unsigned short* Kc = Kh + ((size_t)bh * T_ + kc * 512) * 64;
  const unsigned short* Vc = Vt + (size_t)bh * 64 * T_ + kc * 512;
  unsigned short* Pw = &Ps[w * 2048];
  const int arow = w * 16 + fr;

  for (int kt = 0; kt < 4; ++kt) {
    __syncthreads();
#pragma unroll
    for (int p = 0; p < 4; ++p) {
      int linear = p * 256 + tid;
      int r = linear >> 3, c = linear & 7;
      gload16(Kc + (size_t)(kt * 128 + r) * 64 + (c ^ (r & 7)) * 8, &Ks[linear * 8]);
    }
#pragma unroll
    for (int p = 0; p < 4; ++p) {
      int linear = p * 256 + tid;
      int r = linear >> 4, c = linear & 15;
      gload16(Vc + (size_t)r * T_ + kt * 128 + (c ^ (r & 7)) * 8, &Vs[linear * 8]);
    }
    __syncthreads();

    f32x4 s[8] = {};
    bf16x8 aq[2];
#pragma unroll
    for (int ks = 0; ks < 2; ++ks)
      aq[ks] = *(const bf16x8*)&Qs[arow * 64 + ((ks * 4 + quad) ^ (fr & 7)) * 8];
#pragma unroll
    for (int nf = 0; nf < 8; ++nf) {
      int krow = nf * 16 + fr;
#pragma unroll
      for (int ks = 0; ks < 2; ++ks) {
        bf16x8 bk = *(const bf16x8*)&Ks[krow * 64 + ((ks * 4 + quad) ^ (fr & 7)) * 8];
        s[nf] = __builtin_amdgcn_mfma_f32_16x16x32_bf16(aq[ks], bk, s[nf], 0, 0, 0);
      }
    }
    float alpha[4], rowsum[4];
#pragma unroll
    for (int r = 0; r < 4; ++r) {
      float mt = -3.0e38f;
#pragma unroll
      for (int nf = 0; nf < 8; ++nf) { s[nf][r] *= 0.125f; mt = fmaxf(mt, s[nf][r]); }
#pragma unroll
      for (int x = 1; x < 16; x <<= 1) mt = fmaxf(mt, __shfl_xor(mt, x, 64));
      float mn = fmaxf(m_run[r], mt);
      alpha[r] = exp2f((m_run[r] - mn) * L2E);
      m_run[r] = mn;
      rowsum[r] = 0.f;
    }
#pragma unroll
    for (int nf = 0; nf < 8; ++nf)
#pragma unroll
      for (int r = 0; r < 4; ++r) {
        float p = exp2f((s[nf][r] - m_run[r]) * L2E);
        s[nf][r] = p; rowsum[r] += p;
      }
#pragma unroll
    for (int r = 0; r < 4; ++r) {
#pragma unroll
      for (int x = 1; x < 16; x <<= 1) rowsum[r] += __shfl_xor(rowsum[r], x, 64);
      l_run[r] = l_run[r] * alpha[r] + rowsum[r];
    }
#pragma unroll
    for (int nf = 0; nf < 8; ++nf)
#pragma unroll
      for (int r = 0; r < 4; ++r) {
        int m = quad * 4 + r;
        int c = nf * 2 + (fr >> 3);
        Pw[m * 128 + ((c ^ (m & 7)) * 8) + (fr & 7)] = f2bf(s[nf][r]);
      }
#pragma unroll
    for (int nf2 = 0; nf2 < 4; ++nf2)
#pragma unroll
      for (int r = 0; r < 4; ++r) O[nf2][r] *= alpha[r];
#pragma unroll
    for (int ks2 = 0; ks2 < 4; ++ks2) {
      bf16x8 ap = *(const bf16x8*)&Pw[fr * 128 + (((ks2 * 4 + quad) ^ (fr & 7)) * 8)];
#pragma unroll
      for (int nf2 = 0; nf2 < 4; ++nf2) {
        int vrow = nf2 * 16 + fr;
        bf16x8 bv = *(const bf16x8*)&Vs[vrow * 128 + (((ks2 * 4 + quad) ^ (fr & 7)) * 8)];
        O[nf2] = __builtin_amdgcn_mfma_f32_16x16x32_bf16(ap, bv, O[nf2], 0, 0, 0);
      }
    }
  }

  int qbase = qt * 64 + w * 16;
  float* Ob = Opart + (((size_t)bh * 4 + kc) * 256 + qbase) * 64;
#pragma unroll
  for (int nf2 = 0; nf2 < 4; ++nf2)
#pragma unroll
    for (int r = 0; r < 4; ++r)
      Ob[(size_t)(quad * 4 + r) * 64 + nf2 * 16 + fr] = O[nf2][r];
  if (fr == 0) {
#pragma unroll
    for (int r = 0; r < 4; ++r) {
      size_t mi = ((((size_t)bh * 4 + kc) * 256) + qbase + quad * 4 + r) * 2;
      ml[mi] = m_run[r]; ml[mi + 1] = l_run[r];
    }
  }
}

// ---- combine 4 k-chunk flash partials, scatter into v buffer ------------
__global__ void combine_kernel(const float* __restrict__ Opart,
                               const float* __restrict__ ml,
                               unsigned short* __restrict__ vcomp) {
  int idx = blockIdx.x * 256 + threadIdx.x;  // B*QG*D = 2^19
  int c = idx & (D_ - 1);
  int qi = (idx >> 10) & (QG - 1);
  int b = idx >> 18;
  int h = c >> 6, d = c & 63;
  int bh = b * H_ + h;
  float m[4], l[4];
  float M = -3.0e38f;
#pragma unroll
  for (int ch = 0; ch < 4; ++ch) {
    size_t r = ((size_t)bh * 4 + ch) * 256 + qi;
    m[ch] = ml[r * 2]; l[ch] = ml[r * 2 + 1];
    M = fmaxf(M, m[ch]);
  }
  float osum = 0.f, lsum = 0.f;
#pragma unroll
  for (int ch = 0; ch < 4; ++ch) {
    size_t r = ((size_t)bh * 4 + ch) * 256 + qi;
    float wgt = exp2f((m[ch] - M) * L2E);
    osum += wgt * Opart[r * 64 + d];
    lsum += wgt * l[ch];
  }
  vcomp[((size_t)(b * T_ + qi * 8)) * D_ + c] = f2bf(osum / lsum);
}

extern "C" void kernel_launch(void* const* d_in, const int* in_sizes, int n_in,
                              void* d_out, int out_size, void* d_ws, size_t ws_size,
                              hipStream_t stream) {
  const float* x     = (const float*)d_in[0];
  const float* w_in  = (const float*)d_in[1];
  const float* b_in  = (const float*)d_in[2];
  const float* w_out = (const float*)d_in[3];
  const float* b_out = (const float*)d_in[4];
  const float* w1    = (const float*)d_in[5];
  const float* b1    = (const float*)d_in[6];
  const float* w2    = (const float*)d_in[7];
  const float* b2    = (const float*)d_in[8];
  const float* ln1_g = (const float*)d_in[9];
  const float* ln1_b = (const float*)d_in[10];
  const float* ln2_g = (const float*)d_in[11];
  const float* ln2_b = (const float*)d_in[12];
  float* out = (float*)d_out;

  char* ws = (char*)d_ws;
  size_t off = 0;
  auto alloc = [&](size_t bytes) -> void* {
    void* p = ws + off;
    off += (bytes + 255) & ~(size_t)255;
    return p;
  };
  // persistent-region buffers
  unsigned short* w_inb = (unsigned short*)alloc((size_t)3 * D_ * D_ * 2);
  unsigned short* w_outb= (unsigned short*)alloc((size_t)D_ * D_ * 2);
  unsigned short* w1b   = (unsigned short*)alloc((size_t)MLP_ * D_ * 2);
  unsigned short* w2b   = (unsigned short*)alloc((size_t)D_ * MLP_ * 2);
  unsigned short* vcomp = (unsigned short*)alloc((size_t)NTOK * D_ * 2);  // v, then o
  float*          x1    = (float*)         alloc((size_t)NTOK * D_ * 4);
  unsigned short* xn2   = (unsigned short*)alloc((size_t)NTOK * D_ * 2);
  unsigned short* h     = (unsigned short*)alloc((size_t)NTOK * MLP_ * 2);
  // union region: P2 (2 f32 slabs, 32MB) aliases the attention buffers
  char* U = (char*)alloc((size_t)40 * 1024 * 1024);
  float*          P2    = (float*)U;                                  // 32 MB
  unsigned short* xn    = (unsigned short*)U;                         // 8.0 MB
  unsigned short* Qg    = (unsigned short*)(U + 8388608);             // 4.0 MB
  unsigned short* Kh    = (unsigned short*)(U + 12582912);            // 8.0 MB
  unsigned short* Vt    = (unsigned short*)(U + 20971520);            // 8.0 MB
  float*          Opart = (float*)         (U + 29360128);            // 8.0 MB
  float*          mlbuf = (float*)         (U + 37748736);            // 0.25MB

  // 1. fused weight casts + LN1 (single launch)
  castln_kernel<<<NTOK + NCASTB, 256, 0, stream>>>(
      w_in, w_out, w1, w2, w_inb, w_outb, w1b, w2b, x, ln1_g, ln1_b, xn);

  // 2. QKV = xn @ w_in^T + b_in; routes q->Qg, k->Kh, v->vcomp
  //    (128x256 BK=32 pipelined; 384 blocks, all co-resident, no tail)
  gemm256b_kernel<8><<<dim3(384, 1, 1), 512, 0, stream>>>(
      xn, D_, w_inb, D_, vcomp, 3 * D_, b_in, Qg, Kh, 1024, 12);

  // 3. V transpose for PV B-operand
  vtrans_kernel<<<1024, 256, 0, stream>>>(vcomp, Vt);

  // 4. flash attention over global q-rows (k-split x4 -> 512 blocks)
  flash_kernel<<<dim3(4, 4, 32), 256, 0, stream>>>(Qg, Kh, Vt, Opart, mlbuf);

  // 5. combine k-chunks, scatter into v buffer (o = v elsewhere)
  combine_kernel<<<2048, 256, 0, stream>>>(Opart, mlbuf, vcomp);

  // 6. P2[c] = o @ w_out^T (split-K x2 -> 512 blocks = 2/CU, NT=8)
  gemm128p_kernel<7><<<dim3(8 * 32, 1, 2), 256, 0, stream>>>(
      vcomp, D_, w_outb, D_, P2, (size_t)NTOK * D_, D_, nullptr,
      512, 8, 32);

  // 7. x1 = x + b_out + sum_{c<2}(P2); xn2 = LN2(x1)
  reduce_ln_kernel<<<NTOK, 256, 0, stream>>>(P2, x, b_out, ln2_g, ln2_b, x1, xn2);

  // 8. h = gelu(xn2 @ w1^T + b1)  (256^2 opaque-staged pipeline, R9 proven)
  gemm256a_kernel<2><<<dim3(256, 1, 1), 512, 0, stream>>>(
      xn2, D_, w1b, D_, h, 0, MLP_, b1, 1024, 16);

  // 9. P2[c] = h @ w2^T (split-K x2, gemm128p-opaque, NT=32)
  gemm128p_kernel<7><<<dim3(8 * 32, 1, 2), 256, 0, stream>>>(
      h, MLP_, w2b, MLP_, P2, (size_t)NTOK * D_, D_, nullptr,
      2048, 8, 32);

  // 10. out = x1 + b2 + sum_{c<2}(P2)
  reduce_out_kernel<<<4096, 256, 0, stream>>>(P2, x1, b2, out);
}

// Round 12
// 294.047 us; speedup vs baseline: 1.0853x; 1.0686x over previous
//
#include <hip/hip_runtime.h>

#define D_ 1024
#define T_ 2048
#define B_ 2
#define H_ 16
#define MLP_ 4096
#define NTOK (B_*T_)   // 4096
#define QG 256         // global q-rows per batch (T/8)
#define L2E 1.44269504088896340736f

typedef float f32x4 __attribute__((ext_vector_type(4)));
typedef __bf16 bf16x8 __attribute__((ext_vector_type(8)));

__device__ __forceinline__ unsigned short f2bf(float f) {
  unsigned int u = __float_as_uint(f);
  u += 0x7fff + ((u >> 16) & 1);
  return (unsigned short)(u >> 16);
}

__device__ __forceinline__ float wave_sum(float v) {
  for (int o = 32; o > 0; o >>= 1) v += __shfl_down(v, o, 64);
  return v;
}

// async global->LDS, 16B per lane; LDS dest = wave-uniform base + lane*16
__device__ __forceinline__ void gload16(const unsigned short* g, unsigned short* l) {
  __builtin_amdgcn_global_load_lds(
      (const __attribute__((address_space(1))) void*)g,
      (__attribute__((address_space(3))) void*)l, 16, 0, 0);
}

// 32-bit LDS byte offset of a __shared__ pointer
__device__ __forceinline__ unsigned ldsoff(const void* p) {
  return (unsigned)(size_t)(const __attribute__((address_space(3))) void*)p;
}

// OPAQUE asm staging (R8/R9 proven +9%): global_load_lds_dwordx4 with
// M0 = wave-uniform LDS base (HW adds lane*16). Compiler sees no vmem->LDS
// write, so its waitcnt pass inserts no conservative drains between the
// t+2 prefetch into the currently-read buffer and the phase ds_reads.
__device__ __forceinline__ void agload16(const unsigned short* g, unsigned m0v) {
  unsigned su = __builtin_amdgcn_readfirstlane(m0v);
  asm volatile("s_mov_b32 m0, %0\n\t"
               "global_load_lds_dwordx4 %1, off"
               :: "s"(su), "v"(g) : "memory");
}

// -------- fused: all 4 weight casts + LN1 in ONE launch ------------------
#define N4_WIN  786432   // 3*D*D/4
#define N4_WOUT 262144   // D*D/4
#define N4_W1   1048576  // MLP*D/4
#define N4_W2   1048576  // D*MLP/4
#define NCASTB  12288    // (sum of above)/256
__global__ void castln_kernel(const float* __restrict__ w_in,
                              const float* __restrict__ w_out,
                              const float* __restrict__ w1,
                              const float* __restrict__ w2,
                              unsigned short* __restrict__ o_in,
                              unsigned short* __restrict__ o_out,
                              unsigned short* __restrict__ o1,
                              unsigned short* __restrict__ o2,
                              const float* __restrict__ x,
                              const float* __restrict__ g,
                              const float* __restrict__ b,
                              unsigned short* __restrict__ xn) {
  int blk = blockIdx.x;
  int tid = threadIdx.x;
  if (blk < NTOK) {
    int wave = tid >> 6, lane = tid & 63;
    float4 v = ((const float4*)(x + (size_t)blk * D_))[tid];
    float s  = v.x + v.y + v.z + v.w;
    float s2 = v.x*v.x + v.y*v.y + v.z*v.z + v.w*v.w;
    s = wave_sum(s); s2 = wave_sum(s2);
    __shared__ float r1[4], r2[4];
    if (lane == 0) { r1[wave] = s; r2[wave] = s2; }
    __syncthreads();
    float ts  = r1[0] + r1[1] + r1[2] + r1[3];
    float ts2 = r2[0] + r2[1] + r2[2] + r2[3];
    float mean = ts * (1.0f / D_);
    float var  = ts2 * (1.0f / D_) - mean * mean;
    float rs = rsqrtf(var + 1e-5f);
    float4 gv = ((const float4*)g)[tid];
    float4 bv = ((const float4*)b)[tid];
    ushort4 o;
    o.x = f2bf((v.x - mean) * rs * gv.x + bv.x);
    o.y = f2bf((v.y - mean) * rs * gv.y + bv.y);
    o.z = f2bf((v.z - mean) * rs * gv.z + bv.z);
    o.w = f2bf((v.w - mean) * rs * gv.w + bv.w);
    ((ushort4*)(xn + (size_t)blk * D_))[tid] = o;
  } else {
    int i = (blk - NTOK) * 256 + tid;
    const float* src; unsigned short* dst; int j = i;
    if (i < N4_WIN) { src = w_in; dst = o_in; }
    else if ((j -= N4_WIN) < N4_WOUT) { src = w_out; dst = o_out; }
    else if ((j -= N4_WOUT) < N4_W1) { src = w1; dst = o1; }
    else { j -= N4_W1; src = w2; dst = o2; }
    float4 v = ((const float4*)src)[j];
    ushort4 o;
    o.x = f2bf(v.x); o.y = f2bf(v.y); o.z = f2bf(v.z); o.w = f2bf(v.w);
    ((ushort4*)dst)[j] = o;
  }
}

// ---------------- LayerNorm (one block per row of D=1024), out bf16 ------
__global__ void ln_kernel(const float* __restrict__ x, const float* __restrict__ g,
                          const float* __restrict__ b, unsigned short* __restrict__ out) {
  int row = blockIdx.x;
  int tid = threadIdx.x;
  int wave = tid >> 6, lane = tid & 63;
  float4 v = ((const float4*)(x + (size_t)row * D_))[tid];
  float s  = v.x + v.y + v.z + v.w;
  float s2 = v.x*v.x + v.y*v.y + v.z*v.z + v.w*v.w;
  s = wave_sum(s); s2 = wave_sum(s2);
  __shared__ float r1[4], r2[4];
  if (lane == 0) { r1[wave] = s; r2[wave] = s2; }
  __syncthreads();
  float ts  = r1[0] + r1[1] + r1[2] + r1[3];
  float ts2 = r2[0] + r2[1] + r2[2] + r2[3];
  float mean = ts * (1.0f / D_);
  float var  = ts2 * (1.0f / D_) - mean * mean;
  float rs = rsqrtf(var + 1e-5f);
  float4 gv = ((const float4*)g)[tid];
  float4 bv = ((const float4*)b)[tid];
  ushort4 o;
  o.x = f2bf((v.x - mean) * rs * gv.x + bv.x);
  o.y = f2bf((v.y - mean) * rs * gv.y + bv.y);
  o.z = f2bf((v.z - mean) * rs * gv.z + bv.z);
  o.w = f2bf((v.w - mean) * rs * gv.w + bv.w);
  ((ushort4*)(out + (size_t)row * D_))[tid] = o;
}

// ====== 64x128 tile, BK=64, dbuf pipelined, fused-residual epilogue ======
// Kills the split-K slab machinery for N=1024 GEMMs (out-proj, MLP2):
// grid (M/64)x(N/128) = 512 blocks = 2/CU WITHOUT split-K. LDS 48KB
// (A 2x8KB + B 2x16KB). 4 waves (2M x 2N), wave tile 32x64, 16 MFMA +
// 12 ds_read_b128 per K-tile per wave. Same opaque-staged t+2 pipeline +
// chunk-XOR swizzle as the R9-verified gemm128p (A: 2 slots, B: 4 slots,
// 6 loads/thread/K-tile, counted vmcnt(6)). Epilogue:
//   C[m,n] = acc + bias[n] + xres[m,n]   (f32 out, LDC = D_)
// -> out-proj writes x1 (residual x fused), MLP2 writes out (x1 fused);
// the 32MB slab write + 48MB reduce read per GEMM disappear.
__global__ __launch_bounds__(256)
void gemm64p_kernel(const unsigned short* __restrict__ A, int LDA,
                    const unsigned short* __restrict__ Bm, int LDB,
                    float* __restrict__ C,
                    const float* __restrict__ bias,
                    const float* __restrict__ xres,
                    int K, int nx) {
  __shared__ __align__(16) unsigned short As[2 * 4096];   // [buf][64][64]
  __shared__ __align__(16) unsigned short Bs[2 * 8192];   // [buf][128][64]
  const int tid = threadIdx.x;
  const int lane = tid & 63, wave = tid >> 6;
  const int wm = (wave >> 1) * 32, wn = (wave & 1) * 64;
  const int fr = lane & 15, q = lane >> 4;
  const int f0 = ((q)     ^ (fr & 7)) << 3;
  const int f1 = ((4 + q) ^ (fr & 7)) << 3;

  // XCD-aware swizzle (grid multiple of 8 -> bijective)
  const int nwg = gridDim.x;
  const int bid = blockIdx.x;
  const int l = (bid & 7) * (nwg >> 3) + (bid >> 3);
  const int bx = l % nx, by = l / nx;
  const int m0 = by * 64, n0 = bx * 128;

  // staging sources (chunk-XOR: slot l holds row r=l>>3, chunk (l&7)^(r&7))
  const unsigned short* aS[2];
  const unsigned short* bS[4];
#pragma unroll
  for (int p = 0; p < 2; ++p) {
    int ls = p * 256 + tid;
    int r = ls >> 3;
    int cg = (ls & 7) ^ (r & 7);
    aS[p] = A + (size_t)(m0 + r) * LDA + cg * 8;
  }
#pragma unroll
  for (int p = 0; p < 4; ++p) {
    int ls = p * 256 + tid;
    int r = ls >> 3;
    int cg = (ls & 7) ^ (r & 7);
    bS[p] = Bm + (size_t)(n0 + r) * LDB + cg * 8;
  }
  const int NT = K >> 6;

  const unsigned aW = ldsoff(As) + wave * 1024;
  const unsigned bW = ldsoff(Bs) + wave * 1024;

  // prologue: tile0 -> buf0, tile1 -> buf1 (6 loads each)
#pragma unroll
  for (int p = 0; p < 2; ++p) agload16(aS[p], aW + p * 4096);
#pragma unroll
  for (int p = 0; p < 4; ++p) agload16(bS[p], bW + p * 4096);
#pragma unroll
  for (int p = 0; p < 2; ++p) agload16(aS[p] + 64, aW + 8192 + p * 4096);
#pragma unroll
  for (int p = 0; p < 4; ++p) agload16(bS[p] + 64, bW + 16384 + p * 4096);
  asm volatile("s_waitcnt vmcnt(6)");   // tile0 landed; tile1 in flight
  __builtin_amdgcn_sched_barrier(0);
  __builtin_amdgcn_s_barrier();

  f32x4 acc[2][4] = {};
  for (int t = 0; t < NT; ++t) {
    const int cbA = (t & 1) << 12;        // shorts (4096)
    const int cbB = (t & 1) << 13;        // shorts (8192)
    const unsigned cbAB = (t & 1) << 13;  // bytes (A buf stride 8192)
    const unsigned cbBB = (t & 1) << 14;  // bytes (B buf stride 16384)
    const unsigned short* Ab = As + cbA;
    const unsigned short* Bb = Bs + cbB;
    const int ko2 = (t + 2) << 6;
    {
      bf16x8 af[2], bfr[4];
#pragma unroll
      for (int i = 0; i < 2; ++i) af[i]  = *(const bf16x8*)&Ab[(wm + i * 16 + fr) * 64 + f0];
#pragma unroll
      for (int j = 0; j < 4; ++j) bfr[j] = *(const bf16x8*)&Bb[(wn + j * 16 + fr) * 64 + f0];
#pragma unroll
      for (int i = 0; i < 2; ++i)
#pragma unroll
        for (int j = 0; j < 4; ++j)
          acc[i][j] = __builtin_amdgcn_mfma_f32_16x16x32_bf16(af[i], bfr[j], acc[i][j], 0, 0, 0);
    }
    {
      bf16x8 af[2], bfr[4];
#pragma unroll
      for (int i = 0; i < 2; ++i) af[i]  = *(const bf16x8*)&Ab[(wm + i * 16 + fr) * 64 + f1];
#pragma unroll
      for (int j = 0; j < 4; ++j) bfr[j] = *(const bf16x8*)&Bb[(wn + j * 16 + fr) * 64 + f1];
#pragma unroll
      for (int i = 0; i < 2; ++i)
#pragma unroll
        for (int j = 0; j < 4; ++j)
          acc[i][j] = __builtin_amdgcn_mfma_f32_16x16x32_bf16(af[i], bfr[j], acc[i][j], 0, 0, 0);
    }
    // frag reads of cur buf consumed by MFMAs above
    __builtin_amdgcn_s_barrier();
    if (t + 2 < NT) {
#pragma unroll
      for (int p = 0; p < 2; ++p) agload16(aS[p] + ko2, aW + cbAB + p * 4096);
#pragma unroll
      for (int p = 0; p < 4; ++p) agload16(bS[p] + ko2, bW + cbBB + p * 4096);
    }
    if (t + 1 < NT) {
      if (t + 2 < NT) asm volatile("s_waitcnt vmcnt(6)");   // t+1 landed
      else            asm volatile("s_waitcnt vmcnt(0)");   // tail drain
      __builtin_amdgcn_sched_barrier(0);
    }
    __builtin_amdgcn_s_barrier();
  }

  // epilogue: C = acc + bias + xres  (f32)
  const int col = lane & 15, rbase = (lane >> 4) * 4;
#pragma unroll
  for (int i = 0; i < 2; ++i) {
#pragma unroll
    for (int j = 0; j < 4; ++j) {
      int gn = n0 + wn + j * 16 + col;
      int gmb = m0 + wm + i * 16 + rbase;
      float bv = bias[gn];
#pragma unroll
      for (int r = 0; r < 4; ++r) {
        int gm = gmb + r;
        size_t idx = (size_t)gm * D_ + gn;
        C[idx] = acc[i][j][r] + bv + xres[idx];
      }
    }
  }
}

// ========== 256x256 pipelined GEMM, OPAQUE asm staging (MLP1) ============
// (R8/R9-verified: 47.8us on MLP1.)
template<int EPI>
__global__ __launch_bounds__(512)
void gemm256a_kernel(const unsigned short* __restrict__ A, int LDA,
                     const unsigned short* __restrict__ Bm, int LDB,
                     void* __restrict__ Cv, size_t sC, int LDC,
                     const float* __restrict__ bias,
                     int K, int nx) {
  __shared__ __align__(16) unsigned short As[2 * 16384];
  __shared__ __align__(16) unsigned short Bs[2 * 16384];
  const int tid = threadIdx.x;
  const int lane = tid & 63, w = tid >> 6;
  const int wm = w >> 2, wn = w & 3;
  const int fr = lane & 15, q = lane >> 4, xr = fr & 7;

  const int nwg = gridDim.x;
  const int bid = blockIdx.x;
  const int l = (bid & 7) * (nwg >> 3) + (bid >> 3);
  const int bx = l % nx, by = l / nx;
  const int m0 = by * 256, n0 = bx * 256;
  const int kOff = blockIdx.z * K;

  const unsigned short* aS[4];
  const unsigned short* bS[4];
#pragma unroll
  for (int s = 0; s < 4; ++s) {
    int ls = s * 512 + tid;
    int r = ls >> 3;
    int cg = (ls & 7) ^ (r & 7);
    aS[s] = A  + (size_t)(m0 + r) * LDA + kOff + cg * 8;
    bS[s] = Bm + (size_t)(n0 + r) * LDB + kOff + cg * 8;
  }
  const int NT = K >> 6;

  const unsigned asb = ldsoff(As), bsb = ldsoff(Bs);
  const unsigned aW = asb + w * 1024, bW = bsb + w * 1024;

#pragma unroll
  for (int s = 0; s < 4; ++s) {
    agload16(aS[s], aW + s * 8192);
    agload16(bS[s], bW + s * 8192);
  }
#pragma unroll
  for (int s = 0; s < 4; ++s) {
    agload16(aS[s] + 64, aW + 32768 + s * 8192);
    agload16(bS[s] + 64, bW + 32768 + s * 8192);
  }
  asm volatile("s_waitcnt vmcnt(8)");
  __builtin_amdgcn_sched_barrier(0);
  __builtin_amdgcn_s_barrier();

  const int aOff = ((wm * 128 + fr) << 7) + ((q ^ xr) << 4);
  const int bOff = ((wn * 64 + fr) << 7) + ((q ^ xr) << 4);

  f32x4 acc[8][4] = {};

  for (int t = 0; t < NT; ++t) {
    const int cb = (t & 1) << 15;
    const char* Ab = (const char*)As + cb;
    const char* Bb = (const char*)Bs + cb;
    const unsigned aWc = aW + cb, bWc = bW + cb;
    const int ko2 = (t + 2) << 6;
    bf16x8 af[2][4], bfr[2][4];

#pragma unroll
    for (int i = 0; i < 4; ++i) {
      af[0][i] = *(const bf16x8*)(Ab + aOff + i * 2048);
      af[1][i] = *(const bf16x8*)(Ab + (aOff ^ 64) + i * 2048);
    }
#pragma unroll
    for (int j = 0; j < 2; ++j) {
      bfr[0][j] = *(const bf16x8*)(Bb + bOff + j * 2048);
      bfr[1][j] = *(const bf16x8*)(Bb + (bOff ^ 64) + j * 2048);
    }
    __builtin_amdgcn_s_barrier();
    __builtin_amdgcn_s_setprio(1);
#pragma unroll
    for (int i = 0; i < 4; ++i)
#pragma unroll
      for (int j = 0; j < 2; ++j) {
        acc[i][j] = __builtin_amdgcn_mfma_f32_16x16x32_bf16(af[0][i], bfr[0][j], acc[i][j], 0, 0, 0);
        acc[i][j] = __builtin_amdgcn_mfma_f32_16x16x32_bf16(af[1][i], bfr[1][j], acc[i][j], 0, 0, 0);
      }
    __builtin_amdgcn_s_setprio(0);
    __builtin_amdgcn_s_barrier();

#pragma unroll
    for (int j = 2; j < 4; ++j) {
      bfr[0][j] = *(const bf16x8*)(Bb + bOff + j * 2048);
      bfr[1][j] = *(const bf16x8*)(Bb + (bOff ^ 64) + j * 2048);
    }
    if (t + 2 < NT) {
      agload16(aS[0] + ko2, aWc);
      agload16(aS[2] + ko2, aWc + 16384);
    }
    __builtin_amdgcn_s_barrier();
    __builtin_amdgcn_s_setprio(1);
#pragma unroll
    for (int i = 0; i < 4; ++i)
#pragma unroll
      for (int j = 0; j < 2; ++j) {
        acc[i][2 + j] = __builtin_amdgcn_mfma_f32_16x16x32_bf16(af[0][i], bfr[0][2 + j], acc[i][2 + j], 0, 0, 0);
        acc[i][2 + j] = __builtin_amdgcn_mfma_f32_16x16x32_bf16(af[1][i], bfr[1][2 + j], acc[i][2 + j], 0, 0, 0);
      }
    __builtin_amdgcn_s_setprio(0);
    __builtin_amdgcn_s_barrier();

#pragma unroll
    for (int i = 0; i < 4; ++i) {
      af[0][i] = *(const bf16x8*)(Ab + (aOff + 8192) + i * 2048);
      af[1][i] = *(const bf16x8*)(Ab + ((aOff + 8192) ^ 64) + i * 2048);
    }
    if (t + 2 < NT) {
      agload16(bS[0] + ko2, bWc);
      agload16(bS[1] + ko2, bWc + 8192);
      agload16(bS[2] + ko2, bWc + 16384);
      agload16(bS[3] + ko2, bWc + 24576);
    }
    __builtin_amdgcn_s_barrier();
    __builtin_amdgcn_s_setprio(1);
#pragma unroll
    for (int i = 0; i < 4; ++i)
#pragma unroll
      for (int j = 0; j < 2; ++j) {
        acc[4 + i][j] = __builtin_amdgcn_mfma_f32_16x16x32_bf16(af[0][i], bfr[0][j], acc[4 + i][j], 0, 0, 0);
        acc[4 + i][j] = __builtin_amdgcn_mfma_f32_16x16x32_bf16(af[1][i], bfr[1][j], acc[4 + i][j], 0, 0, 0);
      }
    __builtin_amdgcn_s_setprio(0);
    __builtin_amdgcn_s_barrier();

    if (t + 2 < NT) {
      agload16(aS[1] + ko2, aWc + 8192);
      agload16(aS[3] + ko2, aWc + 24576);
    }
    if (t + 1 < NT) {
      if (t + 2 < NT) asm volatile("s_waitcnt vmcnt(8)");
      else            asm volatile("s_waitcnt vmcnt(0)");
      __builtin_amdgcn_sched_barrier(0);
    }
    __builtin_amdgcn_s_barrier();
    __builtin_amdgcn_s_setprio(1);
#pragma unroll
    for (int i = 0; i < 4; ++i)
#pragma unroll
      for (int j = 0; j < 2; ++j) {
        acc[4 + i][2 + j] = __builtin_amdgcn_mfma_f32_16x16x32_bf16(af[0][i], bfr[0][2 + j], acc[4 + i][2 + j], 0, 0, 0);
        acc[4 + i][2 + j] = __builtin_amdgcn_mfma_f32_16x16x32_bf16(af[1][i], bfr[1][2 + j], acc[4 + i][2 + j], 0, 0, 0);
      }
    __builtin_amdgcn_s_setprio(0);
    __builtin_amdgcn_s_barrier();
  }

  const int col = lane & 15, rbase = (lane >> 4) * 4;
  const int gm0 = m0 + wm * 128 + rbase;
  const int gn0 = n0 + wn * 64 + col;
#pragma unroll
  for (int mi = 0; mi < 8; ++mi) {
#pragma unroll
    for (int j = 0; j < 4; ++j) {
      int gn = gn0 + j * 16;
      float bv = (EPI == 2) ? bias[gn] : 0.0f;
#pragma unroll
      for (int r = 0; r < 4; ++r) {
        int gm = gm0 + mi * 16 + r;
        float v = acc[mi][j][r] + bv;
        if (EPI == 2) {
          float u = v * (1.5957691216f + 0.0713548162f * v * v);
          float gl = v / (1.0f + exp2f(-L2E * u));
          ((unsigned short*)Cv)[(size_t)gm * LDC + gn] = f2bf(gl);
        } else {
          ((float*)Cv)[(size_t)blockIdx.z * sC + (size_t)gm * LDC + gn] = v;
        }
      }
    }
  }
}

// ====== 128x256 tile, BK=32, dbuf pipelined (QKV) ========================
// (R10/R11-verified; 384 blocks, all co-resident.)
template<int EPI>
__global__ __launch_bounds__(512)
void gemm256b_kernel(const unsigned short* __restrict__ A, int LDA,
                     const unsigned short* __restrict__ Bm, int LDB,
                     unsigned short* __restrict__ Cv, int LDC,
                     const float* __restrict__ bias,
                     unsigned short* __restrict__ aux1,
                     unsigned short* __restrict__ aux2,
                     int K, int nx) {
  __shared__ __align__(16) unsigned short As[2 * 4096];   // [buf][128][32]
  __shared__ __align__(16) unsigned short Bs[2 * 8192];   // [buf][256][32]
  const int tid = threadIdx.x;
  const int lane = tid & 63, wv = tid >> 6;
  const int wm = (wv >> 2) * 64, wn = (wv & 3) * 64;
  const int fr = lane & 15, q = lane >> 4;

  const int nwg = gridDim.x;
  const int bid = blockIdx.x;
  const int l = (bid & 7) * (nwg >> 3) + (bid >> 3);
  const int bx = l % nx, by = l / nx;
  const int m0 = by * 128, n0 = bx * 256;

  const int rA = tid >> 2, sA = tid & 3;
  const int cA = sA ^ ((rA >> 1) & 3);
  const unsigned short* aSrc = A  + (size_t)(m0 + rA) * LDA + cA * 8;
  const unsigned short* bSrc0 = Bm + (size_t)(n0 + rA) * LDB + cA * 8;
  const unsigned short* bSrc1 = Bm + (size_t)(n0 + 128 + rA) * LDB + cA * 8;
  const int NT = K >> 5;

  const unsigned aWb = ldsoff(As) + wv * 1024;
  const unsigned bWb = ldsoff(Bs) + wv * 1024;

  agload16(aSrc, aWb);
  agload16(bSrc0, bWb);
  agload16(bSrc1, bWb + 8192);
  agload16(aSrc + 32, aWb + 8192);
  agload16(bSrc0 + 32, bWb + 16384);
  agload16(bSrc1 + 32, bWb + 24576);
  asm volatile("s_waitcnt vmcnt(3)");
  __builtin_amdgcn_sched_barrier(0);
  __builtin_amdgcn_s_barrier();

  f32x4 acc[4][4] = {};
  for (int t = 0; t < NT; ++t) {
    const unsigned cbA = (t & 1) ? 8192u : 0u;
    const unsigned cbB = (t & 1) ? 16384u : 0u;
    const char* Ab = (const char*)As + cbA;
    const char* Bb = (const char*)Bs + cbB;
    const int ko2 = (t + 2) << 5;
    bf16x8 af[4], bfr[4];
#pragma unroll
    for (int i = 0; i < 4; ++i) {
      int ra = wm + i * 16 + fr;
      af[i] = *(const bf16x8*)(Ab + ra * 64 + ((q ^ ((ra >> 1) & 3)) << 4));
    }
#pragma unroll
    for (int j = 0; j < 4; ++j) {
      int rb = wn + j * 16 + fr;
      bfr[j] = *(const bf16x8*)(Bb + rb * 64 + ((q ^ ((rb >> 1) & 3)) << 4));
    }
#pragma unroll
    for (int i = 0; i < 4; ++i)
#pragma unroll
      for (int j = 0; j < 4; ++j)
        acc[i][j] = __builtin_amdgcn_mfma_f32_16x16x32_bf16(af[i], bfr[j], acc[i][j], 0, 0, 0);
    __builtin_amdgcn_s_barrier();
    if (t + 2 < NT) {
      agload16(aSrc + ko2, aWb + cbA);
      agload16(bSrc0 + ko2, bWb + cbB);
      agload16(bSrc1 + ko2, bWb + cbB + 8192);
    }
    if (t + 1 < NT) {
      if (t + 2 < NT) asm volatile("s_waitcnt vmcnt(3)");
      else            asm volatile("s_waitcnt vmcnt(0)");
      __builtin_amdgcn_sched_barrier(0);
    }
    __builtin_amdgcn_s_barrier();
  }

  const int col = lane & 15, rbase = (lane >> 4) * 4;
#pragma unroll
  for (int i = 0; i < 4; ++i) {
#pragma unroll
    for (int j = 0; j < 4; ++j) {
      int gn = n0 + wn + j * 16 + col;
      int gmb = m0 + wm + i * 16 + rbase;
      float bv = bias[gn];
#pragma unroll
      for (int r = 0; r < 4; ++r) {
        int gm = gmb + r;
        float v = acc[i][j][r] + bv;
        if (EPI == 2) {
          float u = v * (1.5957691216f + 0.0713548162f * v * v);
          float gl = v / (1.0f + exp2f(-L2E * u));
          Cv[(size_t)gm * LDC + gn] = f2bf(gl);
        } else {
          int sec = gn >> 10;          // 0=q 1=k 2=v (uniform per block)
          int hh = (gn >> 6) & (H_ - 1);
          int dd = gn & 63;
          int t = gm & (T_ - 1);
          int b = gm >> 11;
          unsigned short bf = f2bf(v);
          if (sec == 0) {
            if (!(t & 7))
              aux1[(((size_t)(b * H_ + hh)) * QG + (t >> 3)) * 64 + dd] = bf;
          } else if (sec == 1) {
            aux2[(((size_t)(b * H_ + hh)) * T_ + t) * 64 + dd] = bf;
          } else {
            Cv[(size_t)gm * D_ + (gn - 2 * D_)] = bf;
          }
        }
      }
    }
  }
}

// ---------------- V transpose: v[tok, D] bf16 -> Vt[bh][d][t] bf16 -------
__global__ void vtrans_kernel(const unsigned short* __restrict__ vcomp,
                              unsigned short* __restrict__ Vt) {
  int blk = blockIdx.x;          // B*H*(T/64) = 1024
  int tchunk = blk & 31;
  int bh = blk >> 5;
  int h = bh & (H_ - 1), b = bh >> 4;
  int t0 = tchunk * 64;
  __shared__ unsigned short ls[64][66];
  int tid = threadIdx.x;
#pragma unroll
  for (int it = 0; it < 16; ++it) {
    int linear = it * 256 + tid;
    int d = linear & 63, tl = linear >> 6;
    ls[d][tl] = vcomp[((size_t)(b * T_ + t0 + tl)) * D_ + h * 64 + d];
  }
  __syncthreads();
#pragma unroll
  for (int it = 0; it < 16; ++it) {
    int linear = it * 256 + tid;
    int tl = linear & 63, d = linear >> 6;
    Vt[((size_t)(bh * 64 + d)) * T_ + t0 + tl] = ls[d][tl];
  }
}

// ---------------- Flash attention for global q-rows ----------------------
__global__ __launch_bounds__(256)
void flash_kernel(const unsigned short* __restrict__ Qg,   // [bh][256][64]
                  const unsigned short* __restrict__ Kh,   // [bh][2048][64]
                  const unsigned short* __restrict__ Vt,   // [bh][64][2048]
                  float* __restrict__ Opart,               // [bh][4][256][64]
                  float* __restrict__ ml) {                // [bh][4][256][2]
  const int kc = blockIdx.x, qt = blockIdx.y, bh = blockIdx.z;
  const int tid = threadIdx.x;
  const int lane = tid & 63, w = tid >> 6;
  const int fr = lane & 15, quad = lane >> 4;

  __shared__ __align__(16) unsigned short Qs[64 * 64];     // 8 KB
  __shared__ __align__(16) unsigned short Ks[128 * 64];    // 16 KB
  __shared__ __align__(16) unsigned short Vs[64 * 128];    // 16 KB
  __shared__ __align__(16) unsigned short Ps[4 * 16 * 128];// 16 KB

  const unsigned short* Qbase = Qg + ((size_t)bh * 256 + qt * 64) * 64;
#pragma unroll
  for (int p = 0; p < 2; ++p) {
    int linear = p * 256 + tid;
    int r = linear >> 3, c = linear & 7;
    gload16(Qbase + r * 64 + (c ^ (r & 7)) * 8, &Qs[linear * 8]);
  }

  float m_run[4], l_run[4];
  f32x4 O[4] = {};
#pragma unroll
  for (int r = 0; r < 4; ++r) { m_run[r] = -3.0e38f; l_run[r] = 0.f; }

  const unsigned short* Kc = Kh + ((size_t)bh * T_ + kc * 512) * 64;
  const unsigned short* Vc = Vt + (size_t)bh * 64 * T_ + kc * 512;
  unsigned short* Pw = &Ps[w * 2048];
  const int arow = w * 16 + fr;

  for (int kt = 0; kt < 4; ++kt) {
    __syncthreads();
#pragma unroll
    for (int p = 0; p < 4; ++p) {
      int linear = p * 256 + tid;
      int r = linear >> 3, c = linear & 7;
      gload16(Kc + (size_t)(kt * 128 + r) * 64 + (c ^ (r & 7)) * 8, &Ks[linear * 8]);
    }
#pragma unroll
    for (int p = 0; p < 4; ++p) {
      int linear = p * 256 + tid;
      int r = linear >> 4, c = linear & 15;
      gload16(Vc + (size_t)r * T_ + kt * 128 + (c ^ (r & 7)) * 8, &Vs[linear * 8]);
    }
    __syncthreads();

    f32x4 s[8] = {};
    bf16x8 aq[2];
#pragma unroll
    for (int ks = 0; ks < 2; ++ks)
      aq[ks] = *(const bf16x8*)&Qs[arow * 64 + ((ks * 4 + quad) ^ (fr & 7)) * 8];
#pragma unroll
    for (int nf = 0; nf < 8; ++nf) {
      int krow = nf * 16 + fr;
#pragma unroll
      for (int ks = 0; ks < 2; ++ks) {
        bf16x8 bk = *(const bf16x8*)&Ks[krow * 64 + ((ks * 4 + quad) ^ (fr & 7)) * 8];
        s[nf] = __builtin_amdgcn_mfma_f32_16x16x32_bf16(aq[ks], bk, s[nf], 0, 0, 0);
      }
    }
    float alpha[4], rowsum[4];
#pragma unroll
    for (int r = 0; r < 4; ++r) {
      float mt = -3.0e38f;
#pragma unroll
      for (int nf = 0; nf < 8; ++nf) { s[nf][r] *= 0.125f; mt = fmaxf(mt, s[nf][r]); }
#pragma unroll
      for (int x = 1; x < 16; x <<= 1) mt = fmaxf(mt, __shfl_xor(mt, x, 64));
      float mn = fmaxf(m_run[r], mt);
      alpha[r] = exp2f((m_run[r] - mn) * L2E);
      m_run[r] = mn;
      rowsum[r] = 0.f;
    }
#pragma unroll
    for (int nf = 0; nf < 8; ++nf)
#pragma unroll
      for (int r = 0; r < 4; ++r) {
        float p = exp2f((s[nf][r] - m_run[r]) * L2E);
        s[nf][r] = p; rowsum[r] += p;
      }
#pragma unroll
    for (int r = 0; r < 4; ++r) {
#pragma unroll
      for (int x = 1; x < 16; x <<= 1) rowsum[r] += __shfl_xor(rowsum[r], x, 64);
      l_run[r] = l_run[r] * alpha[r] + rowsum[r];
    }
#pragma unroll
    for (int nf = 0; nf < 8; ++nf)
#pragma unroll
      for (int r = 0; r < 4; ++r) {
        int m = quad * 4 + r;
        int c = nf * 2 + (fr >> 3);
        Pw[m * 128 + ((c ^ (m & 7)) * 8) + (fr & 7)] = f2bf(s[nf][r]);
      }
#pragma unroll
    for (int nf2 = 0; nf2 < 4; ++nf2)
#pragma unroll
      for (int r = 0; r < 4; ++r) O[nf2][r] *= alpha[r];
#pragma unroll
    for (int ks2 = 0; ks2 < 4; ++ks2) {
      bf16x8 ap = *(const bf16x8*)&Pw[fr * 128 + (((ks2 * 4 + quad) ^ (fr & 7)) * 8)];
#pragma unroll
      for (int nf2 = 0; nf2 < 4; ++nf2) {
        int vrow = nf2 * 16 + fr;
        bf16x8 bv = *(const bf16x8*)&Vs[vrow * 128 + (((ks2 * 4 + quad) ^ (fr & 7)) * 8)];
        O[nf2] = __builtin_amdgcn_mfma_f32_16x16x32_bf16(ap, bv, O[nf2], 0, 0, 0);
      }
    }
  }

  int qbase = qt * 64 + w * 16;
  float* Ob = Opart + (((size_t)bh * 4 + kc) * 256 + qbase) * 64;
#pragma unroll
  for (int nf2 = 0; nf2 < 4; ++nf2)
#pragma unroll
    for (int r = 0; r < 4; ++r)
      Ob[(size_t)(quad * 4 + r) * 64 + nf2 * 16 + fr] = O[nf2][r];
  if (fr == 0) {
#pragma unroll
    for (int r = 0; r < 4; ++r) {
      size_t mi = ((((size_t)bh * 4 + kc) * 256) + qbase + quad * 4 + r) * 2;
      ml[mi] = m_run[r]; ml[mi + 1] = l_run[r];
    }
  }
}

// ---- combine 4 k-chunk flash partials, scatter into v buffer ------------
__global__ void combine_kernel(const float* __restrict__ Opart,
                               const float* __restrict__ ml,
                               unsigned short* __restrict__ vcomp) {
  int idx = blockIdx.x * 256 + threadIdx.x;  // B*QG*D = 2^19
  int c = idx & (D_ - 1);
  int qi = (idx >> 10) & (QG - 1);
  int b = idx >> 18;
  int h = c >> 6, d = c & 63;
  int bh = b * H_ + h;
  float m[4], l[4];
  float M = -3.0e38f;
#pragma unroll
  for (int ch = 0; ch < 4; ++ch) {
    size_t r = ((size_t)bh * 4 + ch) * 256 + qi;
    m[ch] = ml[r * 2]; l[ch] = ml[r * 2 + 1];
    M = fmaxf(M, m[ch]);
  }
  float osum = 0.f, lsum = 0.f;
#pragma unroll
  for (int ch = 0; ch < 4; ++ch) {
    size_t r = ((size_t)bh * 4 + ch) * 256 + qi;
    float wgt = exp2f((m[ch] - M) * L2E);
    osum += wgt * Opart[r * 64 + d];
    lsum += wgt * l[ch];
  }
  vcomp[((size_t)(b * T_ + qi * 8)) * D_ + c] = f2bf(osum / lsum);
}

extern "C" void kernel_launch(void* const* d_in, const int* in_sizes, int n_in,
                              void* d_out, int out_size, void* d_ws, size_t ws_size,
                              hipStream_t stream) {
  const float* x     = (const float*)d_in[0];
  const float* w_in  = (const float*)d_in[1];
  const float* b_in  = (const float*)d_in[2];
  const float* w_out = (const float*)d_in[3];
  const float* b_out = (const float*)d_in[4];
  const float* w1    = (const float*)d_in[5];
  const float* b1    = (const float*)d_in[6];
  const float* w2    = (const float*)d_in[7];
  const float* b2    = (const float*)d_in[8];
  const float* ln1_g = (const float*)d_in[9];
  const float* ln1_b = (const float*)d_in[10];
  const float* ln2_g = (const float*)d_in[11];
  const float* ln2_b = (const float*)d_in[12];
  float* out = (float*)d_out;

  char* ws = (char*)d_ws;
  size_t off = 0;
  auto alloc = [&](size_t bytes) -> void* {
    void* p = ws + off;
    off += (bytes + 255) & ~(size_t)255;
    return p;
  };
  // persistent-region buffers
  unsigned short* w_inb = (unsigned short*)alloc((size_t)3 * D_ * D_ * 2);
  unsigned short* w_outb= (unsigned short*)alloc((size_t)D_ * D_ * 2);
  unsigned short* w1b   = (unsigned short*)alloc((size_t)MLP_ * D_ * 2);
  unsigned short* w2b   = (unsigned short*)alloc((size_t)D_ * MLP_ * 2);
  unsigned short* vcomp = (unsigned short*)alloc((size_t)NTOK * D_ * 2);  // v, then o
  float*          x1    = (float*)         alloc((size_t)NTOK * D_ * 4);
  unsigned short* xn2   = (unsigned short*)alloc((size_t)NTOK * D_ * 2);
  unsigned short* h     = (unsigned short*)alloc((size_t)NTOK * MLP_ * 2);
  // union region: attention buffers (dead after step 5)
  char* U = (char*)alloc((size_t)40 * 1024 * 1024);
  unsigned short* xn    = (unsigned short*)U;                         // 8.0 MB
  unsigned short* Qg    = (unsigned short*)(U + 8388608);             // 4.0 MB
  unsigned short* Kh    = (unsigned short*)(U + 12582912);            // 8.0 MB
  unsigned short* Vt    = (unsigned short*)(U + 20971520);            // 8.0 MB
  float*          Opart = (float*)         (U + 29360128);            // 8.0 MB
  float*          mlbuf = (float*)         (U + 37748736);            // 0.25MB

  // 1. fused weight casts + LN1 (single launch)
  castln_kernel<<<NTOK + NCASTB, 256, 0, stream>>>(
      w_in, w_out, w1, w2, w_inb, w_outb, w1b, w2b, x, ln1_g, ln1_b, xn);

  // 2. QKV = xn @ w_in^T + b_in; routes q->Qg, k->Kh, v->vcomp
  gemm256b_kernel<8><<<dim3(384, 1, 1), 512, 0, stream>>>(
      xn, D_, w_inb, D_, vcomp, 3 * D_, b_in, Qg, Kh, 1024, 12);

  // 3. V transpose for PV B-operand
  vtrans_kernel<<<1024, 256, 0, stream>>>(vcomp, Vt);

  // 4. flash attention over global q-rows (k-split x4 -> 512 blocks)
  flash_kernel<<<dim3(4, 4, 32), 256, 0, stream>>>(Qg, Kh, Vt, Opart, mlbuf);

  // 5. combine k-chunks, scatter into v buffer (o = v elsewhere)
  combine_kernel<<<2048, 256, 0, stream>>>(Opart, mlbuf, vcomp);

  // 6. x1 = x + b_out + o @ w_out^T  (64x128 tiles, 512 blk = 2/CU,
  //    fused residual -- no split-K slabs, no reduce pass)
  gemm64p_kernel<<<dim3(512, 1, 1), 256, 0, stream>>>(
      vcomp, D_, w_outb, D_, x1, b_out, x, 1024, 8);

  // 7. xn2 = LN2(x1)
  ln_kernel<<<NTOK, 256, 0, stream>>>(x1, ln2_g, ln2_b, xn2);

  // 8. h = gelu(xn2 @ w1^T + b1)  (256^2 opaque-staged pipeline)
  gemm256a_kernel<2><<<dim3(256, 1, 1), 512, 0, stream>>>(
      xn2, D_, w1b, D_, h, 0, MLP_, b1, 1024, 16);

  // 9. out = x1 + b2 + h @ w2^T  (64x128 tiles, K=4096 NT=64, fused x1)
  gemm64p_kernel<<<dim3(512, 1, 1), 256, 0, stream>>>(
      h, MLP_, w2b, MLP_, out, b2, x1, 4096, 8);
}